// Round 4
// baseline (1083.541 us; speedup 1.0000x reference)
//
#include <hip/hip_runtime.h>
#include <hip/hip_bf16.h>
#include <math.h>

// Problem constants
#define B_   128
#define H_   512
#define TZ   64
#define TU   128
#define V_   8000
#define VC   8064            // V + TZ
#define LG   16064           // V + VC  (logits row length)
#define GIN  1541            // E + 2H + 5
#define G3   1536            // 3*H

typedef float f32x4 __attribute__((ext_vector_type(4)));
typedef __bf16 bf16x8 __attribute__((ext_vector_type(8)));

__device__ __forceinline__ float sigmoidf_(float x){ return 1.f/(1.f+__expf(-x)); }

// Load 8 consecutive fp32 (16B-aligned) -> bf16x8 fragment.
__device__ __forceinline__ bf16x8 load8_bf16(const float* __restrict__ p){
  float4 x = *(const float4*)p;
  float4 y = *(const float4*)(p+4);
  bf16x8 r;
  r[0]=(__bf16)x.x; r[1]=(__bf16)x.y; r[2]=(__bf16)x.z; r[3]=(__bf16)x.w;
  r[4]=(__bf16)y.x; r[5]=(__bf16)y.y; r[6]=(__bf16)y.z; r[7]=(__bf16)y.w;
  return r;
}
// Predicated scalar version (unaligned / K-tail).
__device__ __forceinline__ bf16x8 load8_bf16_pred(const float* __restrict__ p, int k, int K){
  bf16x8 r;
#pragma unroll
  for (int e = 0; e < 8; ++e)
    r[e] = (__bf16)((k+e < K) ? p[e] : 0.f);
  return r;
}

// ---------------------------------------------------------------------------
// MFMA GEMM: C[M,N] = A[M,K] @ W[N,K]^T + bias[N].
// One wave (64 thr) per 64x64 tile; grid (N/64, M/64).
// Fragment maps (gfx950 16x16x32 bf16, guide-verified):
//   A: row = lane&15, k = k0 + (lane>>4)*8 + i
//   B: col = lane&15, k same slots  (slot-paired => k-permutation-safe)
//   D: col = lane&15, row = (lane>>4)*4 + reg
// ---------------------------------------------------------------------------
template<int ALIGNED>
__global__ __launch_bounds__(64) void mfma_gemm(
    const float* __restrict__ A, int lda,
    const float* __restrict__ W, int ldw,
    const float* __restrict__ bias,
    float* __restrict__ C, int ldc, int K)
{
  const int lane = threadIdx.x;
  const int col = lane & 15, g = lane >> 4;
  const int bm = blockIdx.y * 64, bn = blockIdx.x * 64;
  f32x4 acc[4][4] = {};
  const int kend = ALIGNED ? K : ((K + 31) & ~31);
  for (int k0 = 0; k0 < kend; k0 += 32) {
    const int k = k0 + g*8;
    bf16x8 af[4], bf[4];
#pragma unroll
    for (int i = 0; i < 4; ++i) {
      const float* pa = A + (size_t)(bm + i*16 + col)*lda + k;
      const float* pb = W + (size_t)(bn + i*16 + col)*ldw + k;
      if (ALIGNED) { af[i] = load8_bf16(pa); bf[i] = load8_bf16(pb); }
      else { af[i] = load8_bf16_pred(pa, k, K); bf[i] = load8_bf16_pred(pb, k, K); }
    }
#pragma unroll
    for (int i = 0; i < 4; ++i)
#pragma unroll
      for (int j = 0; j < 4; ++j)
        acc[i][j] = __builtin_amdgcn_mfma_f32_16x16x32_bf16(af[i], bf[j], acc[i][j], 0, 0, 0);
  }
#pragma unroll
  for (int mi = 0; mi < 4; ++mi)
#pragma unroll
    for (int r = 0; r < 4; ++r) {
      int m = bm + mi*16 + g*4 + r;
#pragma unroll
      for (int ni = 0; ni < 4; ++ni) {
        int n = bn + ni*16 + col;
        C[(size_t)m*ldc + n] = acc[mi][ni][r] + bias[n];
      }
    }
}

// ---------------------------------------------------------------------------
// MFMA attention-energy: A rows are enc flattened (T*B, 512); row m -> b=m&127, t=m>>7.
//   score[b*T+t] += sum_n tanh(acc[m][n] + add[b*as + n]) * mul[b*ms + n]
// N = K = 512. Grid (8, M/64), 64 threads. scores pre-zeroed (atomicAdd over 8 N-blocks).
// ---------------------------------------------------------------------------
__global__ __launch_bounds__(64) void mfma_energy(
    const float* __restrict__ A,
    const float* __restrict__ W, int ldw,
    const float* __restrict__ add, int add_stride,
    const float* __restrict__ mul, int mul_stride,
    float* __restrict__ scores, int T)
{
  const int lane = threadIdx.x;
  const int col = lane & 15, g = lane >> 4;
  const int bm = blockIdx.y * 64, bn = blockIdx.x * 64;
  f32x4 acc[4][4] = {};
  for (int k0 = 0; k0 < 512; k0 += 32) {
    const int k = k0 + g*8;
    bf16x8 af[4], bf[4];
#pragma unroll
    for (int i = 0; i < 4; ++i) {
      af[i] = load8_bf16(A + (size_t)(bm + i*16 + col)*512 + k);
      bf[i] = load8_bf16(W + (size_t)(bn + i*16 + col)*ldw + k);
    }
#pragma unroll
    for (int i = 0; i < 4; ++i)
#pragma unroll
      for (int j = 0; j < 4; ++j)
        acc[i][j] = __builtin_amdgcn_mfma_f32_16x16x32_bf16(af[i], bf[j], acc[i][j], 0, 0, 0);
  }
  // Epilogue: tanh, scale, reduce over the 64 n-columns of this tile.
#pragma unroll
  for (int mi = 0; mi < 4; ++mi)
#pragma unroll
    for (int r = 0; r < 4; ++r) {
      int m = bm + mi*16 + g*4 + r;
      int b = m & (B_-1), t = m >> 7;
      float p = 0.f;
#pragma unroll
      for (int ni = 0; ni < 4; ++ni) {
        int n = bn + ni*16 + col;
        float v = tanhf(acc[mi][ni][r] + add[(size_t)b*add_stride + n]);
        p += v * mul[(size_t)b*mul_stride + n];
      }
      p += __shfl_xor(p, 1); p += __shfl_xor(p, 2);
      p += __shfl_xor(p, 4); p += __shfl_xor(p, 8);
      if (col == 0) atomicAdd(&scores[b*T + t], p);
    }
}

// ---------------------------------------------------------------------------
// Per-batch attention softmax over T scores + context: ctx[b,h] = sum_t a[t]*enc[t,b,h]
// ---------------------------------------------------------------------------
__global__ __launch_bounds__(256) void attn_soft_ctx(
    const float* __restrict__ scores, const float* __restrict__ enc,
    float* __restrict__ ctx, int T)
{
  const int b = blockIdx.x, tid = threadIdx.x;
  __shared__ float sa[256];
  __shared__ float aw[128];
  float s = (tid < T) ? scores[b*T + tid] : -INFINITY;
  sa[tid] = s; __syncthreads();
  for (int o = 128; o > 0; o >>= 1) { if (tid < o) sa[tid] = fmaxf(sa[tid], sa[tid+o]); __syncthreads(); }
  float mx = sa[0]; __syncthreads();
  float e = (tid < T) ? __expf(s - mx) : 0.f;
  sa[tid] = e; __syncthreads();
  for (int o = 128; o > 0; o >>= 1) { if (tid < o) sa[tid] += sa[tid+o]; __syncthreads(); }
  float inv = 1.f / sa[0];
  if (tid < T) aw[tid] = e * inv;
  __syncthreads();
  for (int h = tid; h < H_; h += 256) {
    float acc = 0.f;
    for (int t = 0; t < T; ++t)
      acc += aw[t] * enc[((size_t)t*B_ + b)*H_ + h];
    ctx[(size_t)b*H_ + h] = acc;
  }
}

// ---------------------------------------------------------------------------
// Build gru_in (B,1541) = [emb[m_t[b]], u_ctx, z_ctx, degree] and cat3[:, :1024] = [z_ctx, u_ctx]
// ---------------------------------------------------------------------------
__global__ __launch_bounds__(256) void concat_kernel(
    const int* __restrict__ m_t, const float* __restrict__ emb,
    const float* __restrict__ uctx, const float* __restrict__ zctx,
    const float* __restrict__ degree,
    float* __restrict__ gru_in, float* __restrict__ cat3)
{
  const int b = blockIdx.x, tid = threadIdx.x;
  const float* e = emb + (size_t)m_t[b] * H_;
  for (int i = tid; i < H_; i += 256) {
    float uz = uctx[(size_t)b*H_ + i];
    float zz = zctx[(size_t)b*H_ + i];
    gru_in[(size_t)b*GIN + i]          = e[i];
    gru_in[(size_t)b*GIN + H_ + i]     = uz;
    gru_in[(size_t)b*GIN + 2*H_ + i]   = zz;
    cat3[(size_t)b*G3 + i]             = zz;
    cat3[(size_t)b*G3 + H_ + i]        = uz;
  }
  if (tid < 5) gru_in[(size_t)b*GIN + 3*H_ + tid] = degree[b*5 + tid];
}

// ---------------------------------------------------------------------------
// GRU pointwise; writes h_new to ws, cat3[:,1024:1536], and both gru_out outputs.
// ---------------------------------------------------------------------------
__global__ __launch_bounds__(256) void gru_kernel(
    const float* __restrict__ gi, const float* __restrict__ gh,
    const float* __restrict__ hprev,
    float* __restrict__ hnew, float* __restrict__ cat3,
    float* __restrict__ out1, float* __restrict__ out2)
{
  int idx = blockIdx.x*256 + threadIdx.x;        // B*H
  int b = idx >> 9, h = idx & (H_-1);
  float ir = gi[(size_t)b*G3 + h],        hr = gh[(size_t)b*G3 + h];
  float iz = gi[(size_t)b*G3 + H_ + h],   hz = gh[(size_t)b*G3 + H_ + h];
  float in_= gi[(size_t)b*G3 + 2*H_ + h], hn = gh[(size_t)b*G3 + 2*H_ + h];
  float r = sigmoidf_(ir + hr);
  float z = sigmoidf_(iz + hz);
  float n = tanhf(in_ + r*hn);
  float hv = (1.f - z)*n + z*hprev[idx];
  hnew[idx] = hv;
  cat3[(size_t)b*G3 + 2*H_ + h] = hv;
  out1[idx] = hv;
  out2[idx] = hv;
}

// ---------------------------------------------------------------------------
// z_score -> per-row max + exp
// ---------------------------------------------------------------------------
__global__ __launch_bounds__(64) void zexp_kernel(
    const float* __restrict__ zscore, float* __restrict__ e, float* __restrict__ mbuf)
{
  const int b = blockIdx.x, tid = threadIdx.x;   // 64 threads
  __shared__ float sa[64];
  float s = zscore[b*TZ + tid];
  sa[tid] = s; __syncthreads();
  for (int o = 32; o > 0; o >>= 1) { if (tid < o) sa[tid] = fmaxf(sa[tid], sa[tid+o]); __syncthreads(); }
  float mx = sa[0];
  e[b*TZ + tid] = __expf(s - mx);
  if (tid == 0) mbuf[b] = mx;
}

// ---------------------------------------------------------------------------
// z_copy[b,v] = log(sum_t e[t] * sr[b,t,v]) + m[b]  -> logits[b, 8000+v]
// The 264 MB sparse_response read lives here (HBM-bound).
// ---------------------------------------------------------------------------
__global__ __launch_bounds__(256) void zcopy_kernel(
    const float* __restrict__ e, const float* __restrict__ mbuf,
    const float* __restrict__ sr, float* __restrict__ logits)
{
  const int b = blockIdx.y;
  const int v0 = blockIdx.x*1024 + threadIdx.x*4;
  __shared__ float se[TZ];
  if (threadIdx.x < TZ) se[threadIdx.x] = e[b*TZ + threadIdx.x];
  __syncthreads();
  if (v0 >= VC) return;
  float4 acc = {0.f, 0.f, 0.f, 0.f};
  const float* base = sr + (size_t)b*TZ*VC;
#pragma unroll 4
  for (int t = 0; t < TZ; ++t) {
    float et = se[t];
    float4 x = *(const float4*)(base + (size_t)t*VC + v0);
    acc.x += et*x.x; acc.y += et*x.y; acc.z += et*x.z; acc.w += et*x.w;
  }
  float m = mbuf[b];
  float* out = logits + (size_t)b*LG + V_ + v0;
  out[0] = __logf(acc.x) + m;
  out[1] = __logf(acc.y) + m;
  out[2] = __logf(acc.z) + m;
  out[3] = __logf(acc.w) + m;
}

// ---------------------------------------------------------------------------
// Final softmax over 16064 logits per row; proba = [gen + cp[:V], cp[V:]]
// ---------------------------------------------------------------------------
__global__ __launch_bounds__(256) void final_softmax(
    const float* __restrict__ logits, float* __restrict__ out0)
{
  const int b = blockIdx.x, tid = threadIdx.x;
  const float* row = logits + (size_t)b*LG;
  __shared__ float sa[256];
  float mx = -INFINITY;
  for (int i = tid; i < LG; i += 256) mx = fmaxf(mx, row[i]);
  sa[tid] = mx; __syncthreads();
  for (int o = 128; o > 0; o >>= 1) { if (tid < o) sa[tid] = fmaxf(sa[tid], sa[tid+o]); __syncthreads(); }
  mx = sa[0]; __syncthreads();
  float sum = 0.f;
  for (int i = tid; i < LG; i += 256) sum += __expf(row[i] - mx);
  sa[tid] = sum; __syncthreads();
  for (int o = 128; o > 0; o >>= 1) { if (tid < o) sa[tid] += sa[tid+o]; __syncthreads(); }
  float inv = 1.f / sa[0];
  float* o0 = out0 + (size_t)b*VC;
  for (int j = tid; j < V_; j += 256)
    o0[j] = (__expf(row[j]-mx) + __expf(row[V_+j]-mx)) * inv;
  for (int j = tid; j < TZ; j += 256)
    o0[V_ + j] = __expf(row[2*V_ + j] - mx) * inv;
}

// ---------------------------------------------------------------------------
extern "C" void kernel_launch(void* const* d_in, const int* in_sizes, int n_in,
                              void* d_out, int out_size, void* d_ws, size_t ws_size,
                              hipStream_t stream)
{
  const float* z_enc   = (const float*)d_in[0];   // (64,128,512)
  const float* u_enc   = (const float*)d_in[1];   // (128,128,512)
  const int*   m_t     = (const int*)  d_in[2];   // (1,128)
  const float* degree  = (const float*)d_in[3];   // (128,5)
  const float* hidden  = (const float*)d_in[4];   // (1,128,512)
  const float* sr      = (const float*)d_in[5];   // (128,64,8064)
  const float* emb     = (const float*)d_in[6];   // (8000,512)
  const float* attn_z_W= (const float*)d_in[7];   // (512,1024)
  const float* attn_z_b= (const float*)d_in[8];
  const float* attn_z_v= (const float*)d_in[9];
  const float* attn_u_W= (const float*)d_in[10];
  const float* attn_u_b= (const float*)d_in[11];
  const float* attn_u_v= (const float*)d_in[12];
  const float* gru_W_ih= (const float*)d_in[13];  // (1536,1541)
  const float* gru_W_hh= (const float*)d_in[14];  // (1536,512)
  const float* gru_b_ih= (const float*)d_in[15];
  const float* gru_b_hh= (const float*)d_in[16];
  const float* proj_W  = (const float*)d_in[17];  // (8000,1536)
  const float* proj_b  = (const float*)d_in[18];
  const float* copy2_W = (const float*)d_in[19];  // (512,512)
  const float* copy2_b = (const float*)d_in[20];

  float* out0 = (float*)d_out;                        // (128, 8064)
  float* out1 = out0 + (size_t)B_*VC;                 // (128, 512)
  float* out2 = out1 + (size_t)B_*H_;                 // (128, 512)

  // Workspace layout (floats)
  float* ws      = (float*)d_ws;
  float* hWz     = ws;                    // 128*512
  float* hWu     = hWz  + B_*H_;          // 128*512
  float* gh      = hWu  + B_*H_;          // 128*1536
  float* scoresZ = gh   + B_*G3;          // 128*64 (zeroed)
  float* scoresU = scoresZ + B_*TZ;       // 128*128 (zeroed)
  float* zscore  = scoresU + B_*TU;       // 128*64 (zeroed)
  float* zctx    = zscore  + B_*TZ;       // 128*512
  float* uctx    = zctx + B_*H_;          // 128*512
  float* gru_in  = uctx + B_*H_;          // 128*1541
  float* gi      = gru_in + B_*GIN;       // 128*1536
  float* hnew    = gi   + B_*G3;          // 128*512
  float* cat3    = hnew + B_*H_;          // 128*1536
  float* ez      = cat3 + B_*G3;          // 128*64
  float* mz      = ez   + B_*TZ;          // 128
  float* logits  = mz   + B_;             // 128*16064

  // zero the atomic-accumulated score buffers
  (void)hipMemsetAsync(scoresZ, 0, (size_t)(B_*TZ + B_*TU + B_*TZ)*sizeof(float), stream);

  // hidden-side precompute (bias folded here; energy kernels add it per-b)
  mfma_gemm<1><<<dim3(H_/64, 2), 64, 0, stream>>>(hidden, H_, attn_z_W, 2*H_, attn_z_b, hWz, H_, H_);
  mfma_gemm<1><<<dim3(H_/64, 2), 64, 0, stream>>>(hidden, H_, attn_u_W, 2*H_, attn_u_b, hWu, H_, H_);
  mfma_gemm<1><<<dim3(G3/64, 2), 64, 0, stream>>>(hidden, H_, gru_W_hh, H_, gru_b_hh, gh, G3, H_);

  // attention energies + scores (enc part of W starts at column H_)
  mfma_energy<<<dim3(8, TZ*B_/64), 64, 0, stream>>>(z_enc, attn_z_W + H_, 2*H_, hWz, H_, attn_z_v, 0, scoresZ, TZ);
  mfma_energy<<<dim3(8, TU*B_/64), 64, 0, stream>>>(u_enc, attn_u_W + H_, 2*H_, hWu, H_, attn_u_v, 0, scoresU, TU);

  // softmax + context
  attn_soft_ctx<<<B_, 256, 0, stream>>>(scoresZ, z_enc, zctx, TZ);
  attn_soft_ctx<<<B_, 256, 0, stream>>>(scoresU, u_enc, uctx, TU);

  // GRU input concat, input GEMM, pointwise GRU
  concat_kernel<<<B_, 256, 0, stream>>>(m_t, emb, uctx, zctx, degree, gru_in, cat3);
  mfma_gemm<0><<<dim3(G3/64, 2), 64, 0, stream>>>(gru_in, GIN, gru_W_ih, GIN, gru_b_ih, gi, G3, GIN);
  gru_kernel<<<(B_*H_)/256, 256, 0, stream>>>(gi, gh, hidden, hnew, cat3, out1, out2);

  // generation logits -> logits[:, 0:8000]
  mfma_gemm<1><<<dim3(V_/64, 2), 64, 0, stream>>>(cat3, G3, proj_W, G3, proj_b, logits, LG, G3);

  // copy scores
  mfma_energy<<<dim3(8, TZ*B_/64), 64, 0, stream>>>(z_enc, copy2_W, H_, copy2_b, 0, hnew, H_, zscore, TZ);
  zexp_kernel<<<B_, 64, 0, stream>>>(zscore, ez, mz);
  zcopy_kernel<<<dim3((VC + 1023)/1024, B_), 256, 0, stream>>>(ez, mz, sr, logits);

  // final fused softmax + output assembly
  final_softmax<<<B_, 256, 0, stream>>>(logits, out0);
}

// Round 5
// 539.065 us; speedup vs baseline: 2.0100x; 2.0100x over previous
//
#include <hip/hip_runtime.h>
#include <hip/hip_bf16.h>
#include <math.h>

// Problem constants
#define B_   128
#define H_   512
#define TZ   64
#define TU   128
#define V_   8000
#define VC   8064            // V + TZ
#define LG   16064           // V + VC  (logits row length)
#define GIN  1541            // E + 2H + 5
#define GINP 1568            // GIN padded to multiple of 32
#define G3   1536            // 3*H

typedef float f32x4 __attribute__((ext_vector_type(4)));
typedef __bf16 bf16x8 __attribute__((ext_vector_type(8)));

__device__ __forceinline__ float sigmoidf_(float x){ return 1.f/(1.f+__expf(-x)); }

// Load 8 consecutive fp32 (16B-aligned) -> bf16x8 fragment.
__device__ __forceinline__ bf16x8 load8_bf16(const float* __restrict__ p){
  float4 x = *(const float4*)p;
  float4 y = *(const float4*)(p+4);
  bf16x8 r;
  r[0]=(__bf16)x.x; r[1]=(__bf16)x.y; r[2]=(__bf16)x.z; r[3]=(__bf16)x.w;
  r[4]=(__bf16)y.x; r[5]=(__bf16)y.y; r[6]=(__bf16)y.z; r[7]=(__bf16)y.w;
  return r;
}

// ---------------------------------------------------------------------------
// fp32->bf16 convert with row padding: in[rows][incols] f32 -> out[rows][outcols] bf16
// (pad cols zeroed). Used once per call for gru_W_ih.
// ---------------------------------------------------------------------------
__global__ __launch_bounds__(256) void cvt_pad_bf16(
    const float* __restrict__ in, __bf16* __restrict__ out, int rows, int incols, int outcols)
{
  size_t idx = (size_t)blockIdx.x*256 + threadIdx.x;
  size_t total = (size_t)rows*outcols;
  if (idx >= total) return;
  int r = (int)(idx / outcols), c = (int)(idx % outcols);
  out[idx] = (c < incols) ? (__bf16)in[(size_t)r*incols + c] : (__bf16)0.f;
}

// ---------------------------------------------------------------------------
// MFMA GEMM (fp32 in, cvt to bf16): C[M,N] = A[M,K] @ W[N,K]^T + bias[N].
// 256 thr = 4 waves; wave w handles linear tile blockIdx.x*4+w; tile -> (bn,bm).
// Requires: K %32 == 0, rows of A and W 16B-aligned.
// Fragment maps (gfx950 16x16x32 bf16, guide-verified):
//   A: row = lane&15, k = k0 + (lane>>4)*8 + i   (slot-paired with B => safe)
//   D: col = lane&15, row = (lane>>4)*4 + reg
// ---------------------------------------------------------------------------
__global__ __launch_bounds__(256) void mfma_gemm(
    const float* __restrict__ A, int lda,
    const float* __restrict__ W, int ldw,
    const float* __restrict__ bias,
    float* __restrict__ C, int ldc, int K, int nbn, int ntiles)
{
  const int wv = threadIdx.x >> 6, lane = threadIdx.x & 63;
  const int tile = blockIdx.x*4 + wv;
  if (tile >= ntiles) return;
  const int bn = (tile % nbn) * 64, bm = (tile / nbn) * 64;
  const int col = lane & 15, g = lane >> 4;
  f32x4 acc[4][4] = {};
  for (int k0 = 0; k0 < K; k0 += 32) {
    const int k = k0 + g*8;
    bf16x8 af[4], bw[4];
#pragma unroll
    for (int i = 0; i < 4; ++i) {
      af[i] = load8_bf16(A + (size_t)(bm + i*16 + col)*lda + k);
      bw[i] = load8_bf16(W + (size_t)(bn + i*16 + col)*ldw + k);
    }
#pragma unroll
    for (int i = 0; i < 4; ++i)
#pragma unroll
      for (int j = 0; j < 4; ++j)
        acc[i][j] = __builtin_amdgcn_mfma_f32_16x16x32_bf16(af[i], bw[j], acc[i][j], 0, 0, 0);
  }
#pragma unroll
  for (int mi = 0; mi < 4; ++mi)
#pragma unroll
    for (int r = 0; r < 4; ++r) {
      int m = bm + mi*16 + g*4 + r;
#pragma unroll
      for (int ni = 0; ni < 4; ++ni) {
        int n = bn + ni*16 + col;
        C[(size_t)m*ldc + n] = acc[mi][ni][r] + bias[n];
      }
    }
}

// ---------------------------------------------------------------------------
// MFMA GEMM, bf16 direct operands (A and W already bf16, padded/aligned).
// ---------------------------------------------------------------------------
__global__ __launch_bounds__(256) void mfma_gemm_bf16(
    const __bf16* __restrict__ A, int lda,
    const __bf16* __restrict__ W, int ldw,
    const float* __restrict__ bias,
    float* __restrict__ C, int ldc, int K, int nbn, int ntiles)
{
  const int wv = threadIdx.x >> 6, lane = threadIdx.x & 63;
  const int tile = blockIdx.x*4 + wv;
  if (tile >= ntiles) return;
  const int bn = (tile % nbn) * 64, bm = (tile / nbn) * 64;
  const int col = lane & 15, g = lane >> 4;
  f32x4 acc[4][4] = {};
  for (int k0 = 0; k0 < K; k0 += 32) {
    const int k = k0 + g*8;
    bf16x8 af[4], bw[4];
#pragma unroll
    for (int i = 0; i < 4; ++i) {
      af[i] = *(const bf16x8*)(A + (size_t)(bm + i*16 + col)*lda + k);
      bw[i] = *(const bf16x8*)(W + (size_t)(bn + i*16 + col)*ldw + k);
    }
#pragma unroll
    for (int i = 0; i < 4; ++i)
#pragma unroll
      for (int j = 0; j < 4; ++j)
        acc[i][j] = __builtin_amdgcn_mfma_f32_16x16x32_bf16(af[i], bw[j], acc[i][j], 0, 0, 0);
  }
#pragma unroll
  for (int mi = 0; mi < 4; ++mi)
#pragma unroll
    for (int r = 0; r < 4; ++r) {
      int m = bm + mi*16 + g*4 + r;
#pragma unroll
      for (int ni = 0; ni < 4; ++ni) {
        int n = bn + ni*16 + col;
        C[(size_t)m*ldc + n] = acc[mi][ni][r] + bias[n];
      }
    }
}

// ---------------------------------------------------------------------------
// MFMA attention-energy: A rows are enc flattened (T*B, 512); row m -> b=m&127, t=m>>7.
//   score[b*T+t] += sum_n tanh(acc[m][n] + add[b*as + n]) * mul[b*ms + n]
// N = K = 512 fixed; nbn = 8. 4 waves/block via linear tile id.
// scores pre-zeroed (atomicAdd over the 8 n-blocks).
// ---------------------------------------------------------------------------
__global__ __launch_bounds__(256) void mfma_energy(
    const float* __restrict__ A,
    const float* __restrict__ W, int ldw,
    const float* __restrict__ add, int add_stride,
    const float* __restrict__ mul, int mul_stride,
    float* __restrict__ scores, int T, int ntiles)
{
  const int wv = threadIdx.x >> 6, lane = threadIdx.x & 63;
  const int tile = blockIdx.x*4 + wv;
  if (tile >= ntiles) return;
  const int bn = (tile & 7) * 64, bm = (tile >> 3) * 64;
  const int col = lane & 15, g = lane >> 4;
  f32x4 acc[4][4] = {};
  for (int k0 = 0; k0 < 512; k0 += 32) {
    const int k = k0 + g*8;
    bf16x8 af[4], bw[4];
#pragma unroll
    for (int i = 0; i < 4; ++i) {
      af[i] = load8_bf16(A + (size_t)(bm + i*16 + col)*512 + k);
      bw[i] = load8_bf16(W + (size_t)(bn + i*16 + col)*ldw + k);
    }
#pragma unroll
    for (int i = 0; i < 4; ++i)
#pragma unroll
      for (int j = 0; j < 4; ++j)
        acc[i][j] = __builtin_amdgcn_mfma_f32_16x16x32_bf16(af[i], bw[j], acc[i][j], 0, 0, 0);
  }
  // Epilogue: tanh, scale, reduce over the 64 n-columns of this tile.
#pragma unroll
  for (int mi = 0; mi < 4; ++mi)
#pragma unroll
    for (int r = 0; r < 4; ++r) {
      int m = bm + mi*16 + g*4 + r;
      int b = m & (B_-1), t = m >> 7;
      float p = 0.f;
#pragma unroll
      for (int ni = 0; ni < 4; ++ni) {
        int n = bn + ni*16 + col;
        float v = tanhf(acc[mi][ni][r] + add[(size_t)b*add_stride + n]);
        p += v * mul[(size_t)b*mul_stride + n];
      }
      p += __shfl_xor(p, 1); p += __shfl_xor(p, 2);
      p += __shfl_xor(p, 4); p += __shfl_xor(p, 8);
      if (col == 0) atomicAdd(&scores[b*T + t], p);
    }
}

// ---------------------------------------------------------------------------
// Per-batch attention softmax over T scores + context: ctx[b,h] = sum_t a[t]*enc[t,b,h]
// ---------------------------------------------------------------------------
__global__ __launch_bounds__(256) void attn_soft_ctx(
    const float* __restrict__ scores, const float* __restrict__ enc,
    float* __restrict__ ctx, int T)
{
  const int b = blockIdx.x, tid = threadIdx.x;
  __shared__ float sa[256];
  __shared__ float aw[128];
  float s = (tid < T) ? scores[b*T + tid] : -INFINITY;
  sa[tid] = s; __syncthreads();
  for (int o = 128; o > 0; o >>= 1) { if (tid < o) sa[tid] = fmaxf(sa[tid], sa[tid+o]); __syncthreads(); }
  float mx = sa[0]; __syncthreads();
  float e = (tid < T) ? __expf(s - mx) : 0.f;
  sa[tid] = e; __syncthreads();
  for (int o = 128; o > 0; o >>= 1) { if (tid < o) sa[tid] += sa[tid+o]; __syncthreads(); }
  float inv = 1.f / sa[0];
  if (tid < T) aw[tid] = e * inv;
  __syncthreads();
  for (int h = tid; h < H_; h += 256) {
    float acc = 0.f;
    for (int t = 0; t < T; ++t)
      acc += aw[t] * enc[((size_t)t*B_ + b)*H_ + h];
    ctx[(size_t)b*H_ + h] = acc;
  }
}

// ---------------------------------------------------------------------------
// Build gru_in (bf16, padded to GINP) = [emb[m_t[b]], u_ctx, z_ctx, degree, 0-pad]
// and cat3[:, :1024] = [z_ctx, u_ctx]  (fp32, for proj GEMM A).
// ---------------------------------------------------------------------------
__global__ __launch_bounds__(256) void concat_kernel(
    const int* __restrict__ m_t, const float* __restrict__ emb,
    const float* __restrict__ uctx, const float* __restrict__ zctx,
    const float* __restrict__ degree,
    __bf16* __restrict__ gin, float* __restrict__ cat3)
{
  const int b = blockIdx.x, tid = threadIdx.x;
  const float* e = emb + (size_t)m_t[b] * H_;
  for (int i = tid; i < H_; i += 256) {
    float uz = uctx[(size_t)b*H_ + i];
    float zz = zctx[(size_t)b*H_ + i];
    gin[(size_t)b*GINP + i]          = (__bf16)e[i];
    gin[(size_t)b*GINP + H_ + i]     = (__bf16)uz;
    gin[(size_t)b*GINP + 2*H_ + i]   = (__bf16)zz;
    cat3[(size_t)b*G3 + i]           = zz;
    cat3[(size_t)b*G3 + H_ + i]      = uz;
  }
  if (tid < 5) gin[(size_t)b*GINP + 3*H_ + tid] = (__bf16)degree[b*5 + tid];
  if (tid >= 5 && tid < 32) gin[(size_t)b*GINP + GIN + (tid-5)] = (__bf16)0.f;
}

// ---------------------------------------------------------------------------
// GRU pointwise; writes h_new to ws, cat3[:,1024:1536], and both gru_out outputs.
// ---------------------------------------------------------------------------
__global__ __launch_bounds__(256) void gru_kernel(
    const float* __restrict__ gi, const float* __restrict__ gh,
    const float* __restrict__ hprev,
    float* __restrict__ hnew, float* __restrict__ cat3,
    float* __restrict__ out1, float* __restrict__ out2)
{
  int idx = blockIdx.x*256 + threadIdx.x;        // B*H
  int b = idx >> 9, h = idx & (H_-1);
  float ir = gi[(size_t)b*G3 + h],        hr = gh[(size_t)b*G3 + h];
  float iz = gi[(size_t)b*G3 + H_ + h],   hz = gh[(size_t)b*G3 + H_ + h];
  float in_= gi[(size_t)b*G3 + 2*H_ + h], hn = gh[(size_t)b*G3 + 2*H_ + h];
  float r = sigmoidf_(ir + hr);
  float z = sigmoidf_(iz + hz);
  float n = tanhf(in_ + r*hn);
  float hv = (1.f - z)*n + z*hprev[idx];
  hnew[idx] = hv;
  cat3[(size_t)b*G3 + 2*H_ + h] = hv;
  out1[idx] = hv;
  out2[idx] = hv;
}

// ---------------------------------------------------------------------------
// z_score -> per-row max + exp
// ---------------------------------------------------------------------------
__global__ __launch_bounds__(64) void zexp_kernel(
    const float* __restrict__ zscore, float* __restrict__ e, float* __restrict__ mbuf)
{
  const int b = blockIdx.x, tid = threadIdx.x;   // 64 threads
  __shared__ float sa[64];
  float s = zscore[b*TZ + tid];
  sa[tid] = s; __syncthreads();
  for (int o = 32; o > 0; o >>= 1) { if (tid < o) sa[tid] = fmaxf(sa[tid], sa[tid+o]); __syncthreads(); }
  float mx = sa[0];
  e[b*TZ + tid] = __expf(s - mx);
  if (tid == 0) mbuf[b] = mx;
}

// ---------------------------------------------------------------------------
// z_copy[b,v] = log(sum_t e[t] * sr[b,t,v]) + m[b]  -> logits[b, 8000+v]
// The 264 MB sparse_response read lives here (HBM-bound).
// ---------------------------------------------------------------------------
__global__ __launch_bounds__(256) void zcopy_kernel(
    const float* __restrict__ e, const float* __restrict__ mbuf,
    const float* __restrict__ sr, float* __restrict__ logits)
{
  const int b = blockIdx.y;
  const int v0 = blockIdx.x*1024 + threadIdx.x*4;
  __shared__ float se[TZ];
  if (threadIdx.x < TZ) se[threadIdx.x] = e[b*TZ + threadIdx.x];
  __syncthreads();
  if (v0 >= VC) return;
  float4 acc = {0.f, 0.f, 0.f, 0.f};
  const float* base = sr + (size_t)b*TZ*VC;
#pragma unroll 4
  for (int t = 0; t < TZ; ++t) {
    float et = se[t];
    float4 x = *(const float4*)(base + (size_t)t*VC + v0);
    acc.x += et*x.x; acc.y += et*x.y; acc.z += et*x.z; acc.w += et*x.w;
  }
  float m = mbuf[b];
  float* out = logits + (size_t)b*LG + V_ + v0;
  out[0] = __logf(acc.x) + m;
  out[1] = __logf(acc.y) + m;
  out[2] = __logf(acc.z) + m;
  out[3] = __logf(acc.w) + m;
}

// ---------------------------------------------------------------------------
// Final softmax over 16064 logits per row; proba = [gen + cp[:V], cp[V:]]
// ---------------------------------------------------------------------------
__global__ __launch_bounds__(256) void final_softmax(
    const float* __restrict__ logits, float* __restrict__ out0)
{
  const int b = blockIdx.x, tid = threadIdx.x;
  const float* row = logits + (size_t)b*LG;
  __shared__ float sa[256];
  float mx = -INFINITY;
  for (int i = tid; i < LG; i += 256) mx = fmaxf(mx, row[i]);
  sa[tid] = mx; __syncthreads();
  for (int o = 128; o > 0; o >>= 1) { if (tid < o) sa[tid] = fmaxf(sa[tid], sa[tid+o]); __syncthreads(); }
  mx = sa[0]; __syncthreads();
  float sum = 0.f;
  for (int i = tid; i < LG; i += 256) sum += __expf(row[i] - mx);
  sa[tid] = sum; __syncthreads();
  for (int o = 128; o > 0; o >>= 1) { if (tid < o) sa[tid] += sa[tid+o]; __syncthreads(); }
  float inv = 1.f / sa[0];
  float* o0 = out0 + (size_t)b*VC;
  for (int j = tid; j < V_; j += 256)
    o0[j] = (__expf(row[j]-mx) + __expf(row[V_+j]-mx)) * inv;
  for (int j = tid; j < TZ; j += 256)
    o0[V_ + j] = __expf(row[2*V_ + j] - mx) * inv;
}

// ---------------------------------------------------------------------------
extern "C" void kernel_launch(void* const* d_in, const int* in_sizes, int n_in,
                              void* d_out, int out_size, void* d_ws, size_t ws_size,
                              hipStream_t stream)
{
  const float* z_enc   = (const float*)d_in[0];   // (64,128,512)
  const float* u_enc   = (const float*)d_in[1];   // (128,128,512)
  const int*   m_t     = (const int*)  d_in[2];   // (1,128)
  const float* degree  = (const float*)d_in[3];   // (128,5)
  const float* hidden  = (const float*)d_in[4];   // (1,128,512)
  const float* sr      = (const float*)d_in[5];   // (128,64,8064)
  const float* emb     = (const float*)d_in[6];   // (8000,512)
  const float* attn_z_W= (const float*)d_in[7];   // (512,1024)
  const float* attn_z_b= (const float*)d_in[8];
  const float* attn_z_v= (const float*)d_in[9];
  const float* attn_u_W= (const float*)d_in[10];
  const float* attn_u_b= (const float*)d_in[11];
  const float* attn_u_v= (const float*)d_in[12];
  const float* gru_W_ih= (const float*)d_in[13];  // (1536,1541)
  const float* gru_W_hh= (const float*)d_in[14];  // (1536,512)
  const float* gru_b_ih= (const float*)d_in[15];
  const float* gru_b_hh= (const float*)d_in[16];
  const float* proj_W  = (const float*)d_in[17];  // (8000,1536)
  const float* proj_b  = (const float*)d_in[18];
  const float* copy2_W = (const float*)d_in[19];  // (512,512)
  const float* copy2_b = (const float*)d_in[20];

  float* out0 = (float*)d_out;                        // (128, 8064)
  float* out1 = out0 + (size_t)B_*VC;                 // (128, 512)
  float* out2 = out1 + (size_t)B_*H_;                 // (128, 512)

  // Workspace layout (floats)
  float* ws      = (float*)d_ws;
  float* hWz     = ws;                    // 128*512
  float* hWu     = hWz  + B_*H_;          // 128*512
  float* gh      = hWu  + B_*H_;          // 128*1536
  float* scoresZ = gh   + B_*G3;          // 128*64 (zeroed)
  float* scoresU = scoresZ + B_*TZ;       // 128*128 (zeroed)
  float* zscore  = scoresU + B_*TU;       // 128*64 (zeroed)
  float* zctx    = zscore  + B_*TZ;       // 128*512
  float* uctx    = zctx + B_*H_;          // 128*512
  float* gi      = uctx + B_*H_;          // 128*1536
  float* hnew    = gi   + B_*G3;          // 128*512
  float* cat3    = hnew + B_*H_;          // 128*1536
  float* ez      = cat3 + B_*G3;          // 128*64
  float* mz      = ez   + B_*TZ;          // 128
  float* logits  = mz   + B_;             // 128*16064
  __bf16* gin    = (__bf16*)(logits + (size_t)B_*LG);   // 128*1568 bf16
  __bf16* Wp     = gin + (size_t)B_*GINP;               // 1536*1568 bf16

  // zero the atomic-accumulated score buffers
  (void)hipMemsetAsync(scoresZ, 0, (size_t)(B_*TZ + B_*TU + B_*TZ)*sizeof(float), stream);

  // one-time (per call) weight conversion: gru_W_ih fp32[1536][1541] -> bf16[1536][1568]
  {
    size_t total = (size_t)G3 * GINP;
    cvt_pad_bf16<<<(int)((total + 255)/256), 256, 0, stream>>>(gru_W_ih, Wp, G3, GIN, GINP);
  }

  // hidden-side precompute (bias folded here; energy kernels add it per-b)
  mfma_gemm<<<4, 256, 0, stream>>>(hidden, H_, attn_z_W, 2*H_, attn_z_b, hWz, H_, H_, 8, 16);
  mfma_gemm<<<4, 256, 0, stream>>>(hidden, H_, attn_u_W, 2*H_, attn_u_b, hWu, H_, H_, 8, 16);
  mfma_gemm<<<12, 256, 0, stream>>>(hidden, H_, gru_W_hh, H_, gru_b_hh, gh, G3, H_, 24, 48);

  // attention energies + scores (enc part of W starts at column H_)
  mfma_energy<<<(TZ*B_/64)*8/4, 256, 0, stream>>>(z_enc, attn_z_W + H_, 2*H_, hWz, H_, attn_z_v, 0, scoresZ, TZ, TZ*B_/64*8);
  mfma_energy<<<(TU*B_/64)*8/4, 256, 0, stream>>>(u_enc, attn_u_W + H_, 2*H_, hWu, H_, attn_u_v, 0, scoresU, TU, TU*B_/64*8);

  // softmax + context
  attn_soft_ctx<<<B_, 256, 0, stream>>>(scoresZ, z_enc, zctx, TZ);
  attn_soft_ctx<<<B_, 256, 0, stream>>>(scoresU, u_enc, uctx, TU);

  // GRU input concat (bf16 padded), input GEMM (bf16 direct), pointwise GRU
  concat_kernel<<<B_, 256, 0, stream>>>(m_t, emb, uctx, zctx, degree, gin, cat3);
  mfma_gemm_bf16<<<12, 256, 0, stream>>>(gin, GINP, Wp, GINP, gru_b_ih, gi, G3, GINP, 24, 48);
  gru_kernel<<<(B_*H_)/256, 256, 0, stream>>>(gi, gh, hidden, hnew, cat3, out1, out2);

  // generation logits -> logits[:, 0:8000]   (tiles = 125 n * 2 m = 250)
  mfma_gemm<<<63, 256, 0, stream>>>(cat3, G3, proj_W, G3, proj_b, logits, LG, G3, 125, 250);

  // copy scores
  mfma_energy<<<(TZ*B_/64)*8/4, 256, 0, stream>>>(z_enc, copy2_W, H_, copy2_b, 0, hnew, H_, zscore, TZ, TZ*B_/64*8);
  zexp_kernel<<<B_, 64, 0, stream>>>(zscore, ez, mz);
  zcopy_kernel<<<dim3((VC + 1023)/1024, B_), 256, 0, stream>>>(ez, mz, sr, logits);

  // final fused softmax + output assembly
  final_softmax<<<B_, 256, 0, stream>>>(logits, out0);
}

// Round 6
// 511.055 us; speedup vs baseline: 2.1202x; 1.0548x over previous
//
#include <hip/hip_runtime.h>
#include <hip/hip_bf16.h>
#include <math.h>

// Problem constants
#define B_   128
#define H_   512
#define TZ   64
#define TU   128
#define V_   8000
#define VC   8064            // V + TZ
#define LG   16064           // V + VC  (logits row length)
#define GIN  1541            // E + 2H + 5
#define GINP 1568            // GIN padded to multiple of 32
#define G3   1536            // 3*H
#define NB   8               // n-blocks per 512-wide energy GEMM

typedef float f32x4 __attribute__((ext_vector_type(4)));
typedef __bf16 bf16x8 __attribute__((ext_vector_type(8)));

__device__ __forceinline__ float sigmoidf_(float x){ return 1.f/(1.f+__expf(-x)); }

// Load 8 consecutive fp32 (16B-aligned) -> bf16x8 fragment.
__device__ __forceinline__ bf16x8 load8_bf16(const float* __restrict__ p){
  float4 x = *(const float4*)p;
  float4 y = *(const float4*)(p+4);
  bf16x8 r;
  r[0]=(__bf16)x.x; r[1]=(__bf16)x.y; r[2]=(__bf16)x.z; r[3]=(__bf16)x.w;
  r[4]=(__bf16)y.x; r[5]=(__bf16)y.y; r[6]=(__bf16)y.z; r[7]=(__bf16)y.w;
  return r;
}

// ---------------------------------------------------------------------------
// fp32->bf16 convert with row padding: in[rows][incols] f32 -> out[rows][outcols] bf16
// ---------------------------------------------------------------------------
__global__ __launch_bounds__(256) void cvt_pad_bf16(
    const float* __restrict__ in, __bf16* __restrict__ out, int rows, int incols, int outcols)
{
  size_t idx = (size_t)blockIdx.x*256 + threadIdx.x;
  size_t total = (size_t)rows*outcols;
  if (idx >= total) return;
  int r = (int)(idx / outcols), c = (int)(idx % outcols);
  out[idx] = (c < incols) ? (__bf16)in[(size_t)r*incols + c] : (__bf16)0.f;
}

// ---------------------------------------------------------------------------
// MFMA GEMM (fp32 in, cvt to bf16): C[M,N] = A[M,K] @ W[N,K]^T + bias[N].
// 256 thr = 4 waves; wave w handles linear tile blockIdx.x*4+w.
// K %32 == 0, rows 16B-aligned.
// ---------------------------------------------------------------------------
__global__ __launch_bounds__(256) void mfma_gemm(
    const float* __restrict__ A, int lda,
    const float* __restrict__ W, int ldw,
    const float* __restrict__ bias,
    float* __restrict__ C, int ldc, int K, int nbn, int ntiles)
{
  const int wv = threadIdx.x >> 6, lane = threadIdx.x & 63;
  const int tile = blockIdx.x*4 + wv;
  if (tile >= ntiles) return;
  const int bn = (tile % nbn) * 64, bm = (tile / nbn) * 64;
  const int col = lane & 15, g = lane >> 4;
  f32x4 acc[4][4] = {};
  for (int k0 = 0; k0 < K; k0 += 32) {
    const int k = k0 + g*8;
    bf16x8 af[4], bw[4];
#pragma unroll
    for (int i = 0; i < 4; ++i) {
      af[i] = load8_bf16(A + (size_t)(bm + i*16 + col)*lda + k);
      bw[i] = load8_bf16(W + (size_t)(bn + i*16 + col)*ldw + k);
    }
#pragma unroll
    for (int i = 0; i < 4; ++i)
#pragma unroll
      for (int j = 0; j < 4; ++j)
        acc[i][j] = __builtin_amdgcn_mfma_f32_16x16x32_bf16(af[i], bw[j], acc[i][j], 0, 0, 0);
  }
#pragma unroll
  for (int mi = 0; mi < 4; ++mi)
#pragma unroll
    for (int r = 0; r < 4; ++r) {
      int m = bm + mi*16 + g*4 + r;
#pragma unroll
      for (int ni = 0; ni < 4; ++ni) {
        int n = bn + ni*16 + col;
        C[(size_t)m*ldc + n] = acc[mi][ni][r] + bias[n];
      }
    }
}

// ---------------------------------------------------------------------------
// MFMA GEMM, bf16 direct operands (A and W already bf16, padded/aligned).
// ---------------------------------------------------------------------------
__global__ __launch_bounds__(256) void mfma_gemm_bf16(
    const __bf16* __restrict__ A, int lda,
    const __bf16* __restrict__ W, int ldw,
    const float* __restrict__ bias,
    float* __restrict__ C, int ldc, int K, int nbn, int ntiles)
{
  const int wv = threadIdx.x >> 6, lane = threadIdx.x & 63;
  const int tile = blockIdx.x*4 + wv;
  if (tile >= ntiles) return;
  const int bn = (tile % nbn) * 64, bm = (tile / nbn) * 64;
  const int col = lane & 15, g = lane >> 4;
  f32x4 acc[4][4] = {};
  for (int k0 = 0; k0 < K; k0 += 32) {
    const int k = k0 + g*8;
    bf16x8 af[4], bw[4];
#pragma unroll
    for (int i = 0; i < 4; ++i) {
      af[i] = *(const bf16x8*)(A + (size_t)(bm + i*16 + col)*lda + k);
      bw[i] = *(const bf16x8*)(W + (size_t)(bn + i*16 + col)*ldw + k);
    }
#pragma unroll
    for (int i = 0; i < 4; ++i)
#pragma unroll
      for (int j = 0; j < 4; ++j)
        acc[i][j] = __builtin_amdgcn_mfma_f32_16x16x32_bf16(af[i], bw[j], acc[i][j], 0, 0, 0);
  }
#pragma unroll
  for (int mi = 0; mi < 4; ++mi)
#pragma unroll
    for (int r = 0; r < 4; ++r) {
      int m = bm + mi*16 + g*4 + r;
#pragma unroll
      for (int ni = 0; ni < 4; ++ni) {
        int n = bn + ni*16 + col;
        C[(size_t)m*ldc + n] = acc[mi][ni][r] + bias[n];
      }
    }
}

// ---------------------------------------------------------------------------
// MFMA attention-energy: A rows are enc flattened (T*B, 512); row m -> b=m&127, t=m>>7.
//   partial[nb][m'] = sum_{n in nb-block} tanh(acc[m][n] + add[b*as+n]) * mul[b*ms+n]
// where m' = b*T + t. No atomics / no pre-zero: each (nb, row) slot written once.
// N = K = 512 fixed; nbn = 8. 4 waves/block via linear tile id.
// ---------------------------------------------------------------------------
__global__ __launch_bounds__(256) void mfma_energy(
    const float* __restrict__ A,
    const float* __restrict__ W, int ldw,
    const float* __restrict__ add, int add_stride,
    const float* __restrict__ mul, int mul_stride,
    float* __restrict__ partial, int T, int ntiles)
{
  const int wv = threadIdx.x >> 6, lane = threadIdx.x & 63;
  const int tile = blockIdx.x*4 + wv;
  if (tile >= ntiles) return;
  const int nb = tile & 7;
  const int bn = nb * 64, bm = (tile >> 3) * 64;
  const int col = lane & 15, g = lane >> 4;
  f32x4 acc[4][4] = {};
  for (int k0 = 0; k0 < 512; k0 += 32) {
    const int k = k0 + g*8;
    bf16x8 af[4], bw[4];
#pragma unroll
    for (int i = 0; i < 4; ++i) {
      af[i] = load8_bf16(A + (size_t)(bm + i*16 + col)*512 + k);
      bw[i] = load8_bf16(W + (size_t)(bn + i*16 + col)*ldw + k);
    }
#pragma unroll
    for (int i = 0; i < 4; ++i)
#pragma unroll
      for (int j = 0; j < 4; ++j)
        acc[i][j] = __builtin_amdgcn_mfma_f32_16x16x32_bf16(af[i], bw[j], acc[i][j], 0, 0, 0);
  }
  // Epilogue: tanh, scale, reduce over the 64 n-columns of this tile.
#pragma unroll
  for (int mi = 0; mi < 4; ++mi)
#pragma unroll
    for (int r = 0; r < 4; ++r) {
      int m = bm + mi*16 + g*4 + r;
      int b = m & (B_-1), t = m >> 7;
      float p = 0.f;
#pragma unroll
      for (int ni = 0; ni < 4; ++ni) {
        int n = bn + ni*16 + col;
        float v = tanhf(acc[mi][ni][r] + add[(size_t)b*add_stride + n]);
        p += v * mul[(size_t)b*mul_stride + n];
      }
      p += __shfl_xor(p, 1); p += __shfl_xor(p, 2);
      p += __shfl_xor(p, 4); p += __shfl_xor(p, 8);
      if (col == 0) partial[(size_t)nb*(B_*T) + b*T + t] = p;
    }
}

// ---------------------------------------------------------------------------
// Per-batch attention softmax over T scores (summing NB partials) + context.
// ---------------------------------------------------------------------------
__global__ __launch_bounds__(256) void attn_soft_ctx(
    const float* __restrict__ partial, const float* __restrict__ enc,
    float* __restrict__ ctx, int T)
{
  const int b = blockIdx.x, tid = threadIdx.x;
  __shared__ float sa[256];
  __shared__ float aw[128];
  float s = -INFINITY;
  if (tid < T) {
    s = 0.f;
#pragma unroll
    for (int nb = 0; nb < NB; ++nb) s += partial[(size_t)nb*(B_*T) + b*T + tid];
  }
  sa[tid] = s; __syncthreads();
  for (int o = 128; o > 0; o >>= 1) { if (tid < o) sa[tid] = fmaxf(sa[tid], sa[tid+o]); __syncthreads(); }
  float mx = sa[0]; __syncthreads();
  float e = (tid < T) ? __expf(s - mx) : 0.f;
  sa[tid] = e; __syncthreads();
  for (int o = 128; o > 0; o >>= 1) { if (tid < o) sa[tid] += sa[tid+o]; __syncthreads(); }
  float inv = 1.f / sa[0];
  if (tid < T) aw[tid] = e * inv;
  __syncthreads();
  for (int h = tid; h < H_; h += 256) {
    float acc = 0.f;
    for (int t = 0; t < T; ++t)
      acc += aw[t] * enc[((size_t)t*B_ + b)*H_ + h];
    ctx[(size_t)b*H_ + h] = acc;
  }
}

// ---------------------------------------------------------------------------
// Build gru_in (bf16, padded to GINP) and cat3[:, :1024] = [z_ctx, u_ctx].
// ---------------------------------------------------------------------------
__global__ __launch_bounds__(256) void concat_kernel(
    const int* __restrict__ m_t, const float* __restrict__ emb,
    const float* __restrict__ uctx, const float* __restrict__ zctx,
    const float* __restrict__ degree,
    __bf16* __restrict__ gin, float* __restrict__ cat3)
{
  const int b = blockIdx.x, tid = threadIdx.x;
  const float* e = emb + (size_t)m_t[b] * H_;
  for (int i = tid; i < H_; i += 256) {
    float uz = uctx[(size_t)b*H_ + i];
    float zz = zctx[(size_t)b*H_ + i];
    gin[(size_t)b*GINP + i]          = (__bf16)e[i];
    gin[(size_t)b*GINP + H_ + i]     = (__bf16)uz;
    gin[(size_t)b*GINP + 2*H_ + i]   = (__bf16)zz;
    cat3[(size_t)b*G3 + i]           = zz;
    cat3[(size_t)b*G3 + H_ + i]      = uz;
  }
  if (tid < 5) gin[(size_t)b*GINP + 3*H_ + tid] = (__bf16)degree[b*5 + tid];
  if (tid >= 5 && tid < 32) gin[(size_t)b*GINP + GIN + (tid-5)] = (__bf16)0.f;
}

// ---------------------------------------------------------------------------
// GRU pointwise; writes h_new to ws, cat3[:,1024:1536], and both gru_out outputs.
// ---------------------------------------------------------------------------
__global__ __launch_bounds__(256) void gru_kernel(
    const float* __restrict__ gi, const float* __restrict__ gh,
    const float* __restrict__ hprev,
    float* __restrict__ hnew, float* __restrict__ cat3,
    float* __restrict__ out1, float* __restrict__ out2)
{
  int idx = blockIdx.x*256 + threadIdx.x;        // B*H
  int b = idx >> 9, h = idx & (H_-1);
  float ir = gi[(size_t)b*G3 + h],        hr = gh[(size_t)b*G3 + h];
  float iz = gi[(size_t)b*G3 + H_ + h],   hz = gh[(size_t)b*G3 + H_ + h];
  float in_= gi[(size_t)b*G3 + 2*H_ + h], hn = gh[(size_t)b*G3 + 2*H_ + h];
  float r = sigmoidf_(ir + hr);
  float z = sigmoidf_(iz + hz);
  float n = tanhf(in_ + r*hn);
  float hv = (1.f - z)*n + z*hprev[idx];
  hnew[idx] = hv;
  cat3[(size_t)b*G3 + 2*H_ + h] = hv;
  out1[idx] = hv;
  out2[idx] = hv;
}

// ---------------------------------------------------------------------------
// z_score partials -> per-row max + exp
// ---------------------------------------------------------------------------
__global__ __launch_bounds__(64) void zexp_kernel(
    const float* __restrict__ partial, float* __restrict__ e, float* __restrict__ mbuf)
{
  const int b = blockIdx.x, tid = threadIdx.x;   // 64 threads
  __shared__ float sa[64];
  float s = 0.f;
#pragma unroll
  for (int nb = 0; nb < NB; ++nb) s += partial[(size_t)nb*(B_*TZ) + b*TZ + tid];
  sa[tid] = s; __syncthreads();
  for (int o = 32; o > 0; o >>= 1) { if (tid < o) sa[tid] = fmaxf(sa[tid], sa[tid+o]); __syncthreads(); }
  float mx = sa[0];
  e[b*TZ + tid] = __expf(s - mx);
  if (tid == 0) mbuf[b] = mx;
}

// ---------------------------------------------------------------------------
// z_copy[b,v] = log(sum_t e[t] * sr[b,t,v]) + m[b]  -> logits[b, 8000+v]
// ---------------------------------------------------------------------------
__global__ __launch_bounds__(256) void zcopy_kernel(
    const float* __restrict__ e, const float* __restrict__ mbuf,
    const float* __restrict__ sr, float* __restrict__ logits)
{
  const int b = blockIdx.y;
  const int v0 = blockIdx.x*1024 + threadIdx.x*4;
  __shared__ float se[TZ];
  if (threadIdx.x < TZ) se[threadIdx.x] = e[b*TZ + threadIdx.x];
  __syncthreads();
  if (v0 >= VC) return;
  float4 acc = {0.f, 0.f, 0.f, 0.f};
  const float* base = sr + (size_t)b*TZ*VC;
#pragma unroll 4
  for (int t = 0; t < TZ; ++t) {
    float et = se[t];
    float4 x = *(const float4*)(base + (size_t)t*VC + v0);
    acc.x += et*x.x; acc.y += et*x.y; acc.z += et*x.z; acc.w += et*x.w;
  }
  float m = mbuf[b];
  float* out = logits + (size_t)b*LG + V_ + v0;
  out[0] = __logf(acc.x) + m;
  out[1] = __logf(acc.y) + m;
  out[2] = __logf(acc.z) + m;
  out[3] = __logf(acc.w) + m;
}

// ---------------------------------------------------------------------------
// Final softmax over 16064 logits per row; proba = [gen + cp[:V], cp[V:]]
// ---------------------------------------------------------------------------
__global__ __launch_bounds__(256) void final_softmax(
    const float* __restrict__ logits, float* __restrict__ out0)
{
  const int b = blockIdx.x, tid = threadIdx.x;
  const float* row = logits + (size_t)b*LG;
  __shared__ float sa[256];
  float mx = -INFINITY;
  for (int i = tid; i < LG; i += 256) mx = fmaxf(mx, row[i]);
  sa[tid] = mx; __syncthreads();
  for (int o = 128; o > 0; o >>= 1) { if (tid < o) sa[tid] = fmaxf(sa[tid], sa[tid+o]); __syncthreads(); }
  mx = sa[0]; __syncthreads();
  float sum = 0.f;
  for (int i = tid; i < LG; i += 256) sum += __expf(row[i] - mx);
  sa[tid] = sum; __syncthreads();
  for (int o = 128; o > 0; o >>= 1) { if (tid < o) sa[tid] += sa[tid+o]; __syncthreads(); }
  float inv = 1.f / sa[0];
  float* o0 = out0 + (size_t)b*VC;
  for (int j = tid; j < V_; j += 256)
    o0[j] = (__expf(row[j]-mx) + __expf(row[V_+j]-mx)) * inv;
  for (int j = tid; j < TZ; j += 256)
    o0[V_ + j] = __expf(row[2*V_ + j] - mx) * inv;
}

// ---------------------------------------------------------------------------
extern "C" void kernel_launch(void* const* d_in, const int* in_sizes, int n_in,
                              void* d_out, int out_size, void* d_ws, size_t ws_size,
                              hipStream_t stream)
{
  const float* z_enc   = (const float*)d_in[0];   // (64,128,512)
  const float* u_enc   = (const float*)d_in[1];   // (128,128,512)
  const int*   m_t     = (const int*)  d_in[2];   // (1,128)
  const float* degree  = (const float*)d_in[3];   // (128,5)
  const float* hidden  = (const float*)d_in[4];   // (1,128,512)
  const float* sr      = (const float*)d_in[5];   // (128,64,8064)
  const float* emb     = (const float*)d_in[6];   // (8000,512)
  const float* attn_z_W= (const float*)d_in[7];   // (512,1024)
  const float* attn_z_b= (const float*)d_in[8];
  const float* attn_z_v= (const float*)d_in[9];
  const float* attn_u_W= (const float*)d_in[10];
  const float* attn_u_b= (const float*)d_in[11];
  const float* attn_u_v= (const float*)d_in[12];
  const float* gru_W_ih= (const float*)d_in[13];  // (1536,1541)
  const float* gru_W_hh= (const float*)d_in[14];  // (1536,512)
  const float* gru_b_ih= (const float*)d_in[15];
  const float* gru_b_hh= (const float*)d_in[16];
  const float* proj_W  = (const float*)d_in[17];  // (8000,1536)
  const float* proj_b  = (const float*)d_in[18];
  const float* copy2_W = (const float*)d_in[19];  // (512,512)
  const float* copy2_b = (const float*)d_in[20];

  float* out0 = (float*)d_out;                        // (128, 8064)
  float* out1 = out0 + (size_t)B_*VC;                 // (128, 512)
  float* out2 = out1 + (size_t)B_*H_;                 // (128, 512)

  // Workspace layout (floats)
  float* ws      = (float*)d_ws;
  float* hWz     = ws;                    // 128*512
  float* hWu     = hWz  + B_*H_;          // 128*512
  float* gh      = hWu  + B_*H_;          // 128*1536
  float* partZ   = gh   + B_*G3;          // 8*128*64
  float* partU   = partZ + NB*B_*TZ;      // 8*128*128
  float* partC   = partU + NB*B_*TU;      // 8*128*64
  float* zctx    = partC + NB*B_*TZ;      // 128*512
  float* uctx    = zctx + B_*H_;          // 128*512
  float* gi      = uctx + B_*H_;          // 128*1536
  float* hnew    = gi   + B_*G3;          // 128*512
  float* cat3    = hnew + B_*H_;          // 128*1536
  float* ez      = cat3 + B_*G3;          // 128*64
  float* mz      = ez   + B_*TZ;          // 128
  float* logits  = mz   + B_;             // 128*16064
  __bf16* gin    = (__bf16*)(logits + (size_t)B_*LG);   // 128*1568 bf16
  __bf16* Wp     = gin + (size_t)B_*GINP;               // 1536*1568 bf16

  // one-time (per call) weight conversion: gru_W_ih fp32[1536][1541] -> bf16[1536][1568]
  {
    size_t total = (size_t)G3 * GINP;
    cvt_pad_bf16<<<(int)((total + 255)/256), 256, 0, stream>>>(gru_W_ih, Wp, G3, GIN, GINP);
  }

  // hidden-side precompute (bias folded here; energy kernels add it per-b)
  mfma_gemm<<<4, 256, 0, stream>>>(hidden, H_, attn_z_W, 2*H_, attn_z_b, hWz, H_, H_, 8, 16);
  mfma_gemm<<<4, 256, 0, stream>>>(hidden, H_, attn_u_W, 2*H_, attn_u_b, hWu, H_, H_, 8, 16);
  mfma_gemm<<<12, 256, 0, stream>>>(hidden, H_, gru_W_hh, H_, gru_b_hh, gh, G3, H_, 24, 48);

  // attention energies -> per-n-block partial sums (no atomics, no pre-zero)
  mfma_energy<<<(TZ*B_/64)*NB/4, 256, 0, stream>>>(z_enc, attn_z_W + H_, 2*H_, hWz, H_, attn_z_v, 0, partZ, TZ, TZ*B_/64*NB);
  mfma_energy<<<(TU*B_/64)*NB/4, 256, 0, stream>>>(u_enc, attn_u_W + H_, 2*H_, hWu, H_, attn_u_v, 0, partU, TU, TU*B_/64*NB);

  // softmax + context
  attn_soft_ctx<<<B_, 256, 0, stream>>>(partZ, z_enc, zctx, TZ);
  attn_soft_ctx<<<B_, 256, 0, stream>>>(partU, u_enc, uctx, TU);

  // GRU input concat (bf16 padded), input GEMM (bf16 direct), pointwise GRU
  concat_kernel<<<B_, 256, 0, stream>>>(m_t, emb, uctx, zctx, degree, gin, cat3);
  mfma_gemm_bf16<<<12, 256, 0, stream>>>(gin, GINP, Wp, GINP, gru_b_ih, gi, G3, GINP, 24, 48);
  gru_kernel<<<(B_*H_)/256, 256, 0, stream>>>(gi, gh, hidden, hnew, cat3, out1, out2);

  // generation logits -> logits[:, 0:8000]   (tiles = 125 n * 2 m = 250)
  mfma_gemm<<<63, 256, 0, stream>>>(cat3, G3, proj_W, G3, proj_b, logits, LG, G3, 125, 250);

  // copy scores
  mfma_energy<<<(TZ*B_/64)*NB/4, 256, 0, stream>>>(z_enc, copy2_W, H_, copy2_b, 0, hnew, H_, partC, TZ, TZ*B_/64*NB);
  zexp_kernel<<<B_, 64, 0, stream>>>(partC, ez, mz);
  zcopy_kernel<<<dim3((VC + 1023)/1024, B_), 256, 0, stream>>>(ez, mz, sr, logits);

  // final fused softmax + output assembly
  final_softmax<<<B_, 256, 0, stream>>>(logits, out0);
}

// Round 7
// 374.073 us; speedup vs baseline: 2.8966x; 1.3662x over previous
//
#include <hip/hip_runtime.h>
#include <hip/hip_bf16.h>
#include <math.h>

// Problem constants
#define B_   128
#define H_   512
#define TZ   64
#define TU   128
#define V_   8000
#define VC   8064            // V + TZ
#define GIN  1541            // E + 2H + 5
#define GINP 1568            // GIN padded to multiple of 32
#define G3   1536            // 3*H
#define NB   8               // n-blocks per 512-wide energy GEMM

typedef float f32x4 __attribute__((ext_vector_type(4)));
typedef __bf16 bf16x8 __attribute__((ext_vector_type(8)));

__device__ __forceinline__ float sigmoidf_(float x){ return 1.f/(1.f+__expf(-x)); }

__device__ __forceinline__ void cvt8(const float* __restrict__ s, __bf16* __restrict__ d){
  float4 x = *(const float4*)s;
  float4 y = *(const float4*)(s+4);
  bf16x8 r;
  r[0]=(__bf16)x.x; r[1]=(__bf16)x.y; r[2]=(__bf16)x.z; r[3]=(__bf16)x.w;
  r[4]=(__bf16)y.x; r[5]=(__bf16)y.y; r[6]=(__bf16)y.z; r[7]=(__bf16)y.w;
  *(bf16x8*)d = r;
}

// ---------------------------------------------------------------------------
// One-pass fp32->bf16 conversion of all MFMA operands. Unit = 8 elements.
// ---------------------------------------------------------------------------
#define U_Z   524288u     // z_enc  4194304
#define U_U   1048576u    // u_enc  8388608
#define U_H   8192u       // hidden 65536
#define U_ZW  65536u      // attn_z_W 524288
#define U_UW  65536u      // attn_u_W 524288
#define U_CW  32768u      // copy2_W 262144
#define U_WHH 98304u      // gru_W_hh 786432
#define U_PW  1536000u    // proj_W 12288000
#define CVT_UNITS (U_Z+U_U+U_H+U_ZW+U_UW+U_CW+U_WHH+U_PW)   // 3379200

__global__ __launch_bounds__(256) void cvt_all(
    const float* __restrict__ z, const float* __restrict__ u, const float* __restrict__ hid,
    const float* __restrict__ zW, const float* __restrict__ uW, const float* __restrict__ cW,
    const float* __restrict__ whh, const float* __restrict__ pW,
    __bf16* __restrict__ zb, __bf16* __restrict__ ub, __bf16* __restrict__ hb,
    __bf16* __restrict__ zWb, __bf16* __restrict__ uWb, __bf16* __restrict__ cWb,
    __bf16* __restrict__ whhb, __bf16* __restrict__ pWb)
{
  unsigned t = blockIdx.x*256u + threadIdx.x;
  if (t >= CVT_UNITS) return;
  const float* s; __bf16* d; unsigned o = t;
  if      (o < U_Z)                   { s=z;   d=zb;   }
  else if ((o-=U_Z)   < U_U)          { s=u;   d=ub;   }
  else if ((o-=U_U)   < U_H)          { s=hid; d=hb;   }
  else if ((o-=U_H)   < U_ZW)         { s=zW;  d=zWb;  }
  else if ((o-=U_ZW)  < U_UW)         { s=uW;  d=uWb;  }
  else if ((o-=U_UW)  < U_CW)         { s=cW;  d=cWb;  }
  else if ((o-=U_CW)  < U_WHH)        { s=whh; d=whhb; }
  else     { o-=U_WHH;                  s=pW;  d=pWb;  }
  cvt8(s + (size_t)o*8, d + (size_t)o*8);
}

// ---------------------------------------------------------------------------
// fp32->bf16 with row padding (gru_W_ih 1536x1541 -> 1536x1568)
// ---------------------------------------------------------------------------
__global__ __launch_bounds__(256) void cvt_pad_bf16(
    const float* __restrict__ in, __bf16* __restrict__ out, int rows, int incols, int outcols)
{
  size_t idx = (size_t)blockIdx.x*256 + threadIdx.x;
  size_t total = (size_t)rows*outcols;
  if (idx >= total) return;
  int r = (int)(idx / outcols), c = (int)(idx % outcols);
  out[idx] = (c < incols) ? (__bf16)in[(size_t)r*incols + c] : (__bf16)0.f;
}

// ---------------------------------------------------------------------------
// MFMA GEMM, bf16 operands: C[M,N] = A @ W^T + bias. 4 waves/block, 64x64/wave.
// ---------------------------------------------------------------------------
__global__ __launch_bounds__(256) void mfma_gemm_bf16(
    const __bf16* __restrict__ A, int lda,
    const __bf16* __restrict__ W, int ldw,
    const float* __restrict__ bias,
    float* __restrict__ C, int ldc, int K, int nbn, int ntiles)
{
  const int wv = threadIdx.x >> 6, lane = threadIdx.x & 63;
  const int tile = blockIdx.x*4 + wv;
  if (tile >= ntiles) return;
  const int bn = (tile % nbn) * 64, bm = (tile / nbn) * 64;
  const int col = lane & 15, g = lane >> 4;
  f32x4 acc[4][4] = {};
  for (int k0 = 0; k0 < K; k0 += 32) {
    const int k = k0 + g*8;
    bf16x8 af[4], bw[4];
#pragma unroll
    for (int i = 0; i < 4; ++i) {
      af[i] = *(const bf16x8*)(A + (size_t)(bm + i*16 + col)*lda + k);
      bw[i] = *(const bf16x8*)(W + (size_t)(bn + i*16 + col)*ldw + k);
    }
#pragma unroll
    for (int i = 0; i < 4; ++i)
#pragma unroll
      for (int j = 0; j < 4; ++j)
        acc[i][j] = __builtin_amdgcn_mfma_f32_16x16x32_bf16(af[i], bw[j], acc[i][j], 0, 0, 0);
  }
#pragma unroll
  for (int mi = 0; mi < 4; ++mi)
#pragma unroll
    for (int r = 0; r < 4; ++r) {
      int m = bm + mi*16 + g*4 + r;
#pragma unroll
      for (int ni = 0; ni < 4; ++ni) {
        int n = bn + ni*16 + col;
        C[(size_t)m*ldc + n] = acc[mi][ni][r] + bias[n];
      }
    }
}

// ---------------------------------------------------------------------------
// Proj GEMM with K-split x3: partial[s][128][8000] = cat3b[:, s*512:(s+1)*512] @ projWb^T
// 750 tiles; no bias (added in final_softmax2).
// ---------------------------------------------------------------------------
__global__ __launch_bounds__(256) void mfma_proj(
    const __bf16* __restrict__ A,      // cat3b [128][1536]
    const __bf16* __restrict__ W,      // projWb [8000][1536]
    float* __restrict__ P)             // 3 x [128][8000]
{
  const int wv = threadIdx.x >> 6, lane = threadIdx.x & 63;
  const int tile = blockIdx.x*4 + wv;
  if (tile >= 750) return;
  const int s = tile / 250, t2 = tile % 250;
  const int bn = (t2 % 125) * 64, bm = (t2 / 125) * 64;
  const int col = lane & 15, g = lane >> 4;
  const __bf16* As = A + s*512;
  const __bf16* Ws = W + s*512;
  float* C = P + (size_t)s*B_*V_;
  f32x4 acc[4][4] = {};
  for (int k0 = 0; k0 < 512; k0 += 32) {
    const int k = k0 + g*8;
    bf16x8 af[4], bw[4];
#pragma unroll
    for (int i = 0; i < 4; ++i) {
      af[i] = *(const bf16x8*)(As + (size_t)(bm + i*16 + col)*G3 + k);
      bw[i] = *(const bf16x8*)(Ws + (size_t)(bn + i*16 + col)*G3 + k);
    }
#pragma unroll
    for (int i = 0; i < 4; ++i)
#pragma unroll
      for (int j = 0; j < 4; ++j)
        acc[i][j] = __builtin_amdgcn_mfma_f32_16x16x32_bf16(af[i], bw[j], acc[i][j], 0, 0, 0);
  }
#pragma unroll
  for (int mi = 0; mi < 4; ++mi)
#pragma unroll
    for (int r = 0; r < 4; ++r) {
      int m = bm + mi*16 + g*4 + r;
#pragma unroll
      for (int ni = 0; ni < 4; ++ni)
        C[(size_t)m*V_ + bn + ni*16 + col] = acc[mi][ni][r];
    }
}

// ---------------------------------------------------------------------------
// Fused attention-energy (two problem sets selected by tile id; bf16 operands).
//   partial[nb][b*T+t] = sum_{n in nb-block} tanh(acc + add[b*as+n]) * mul[b*ms+n]
// ---------------------------------------------------------------------------
__global__ __launch_bounds__(256) void mfma_energy2(
    const __bf16* __restrict__ Az, const __bf16* __restrict__ Wz, int ldwz,
    const float* __restrict__ addz, int asz, const float* __restrict__ mulz, int msz,
    float* __restrict__ outz, int Tz,
    const __bf16* __restrict__ Au, const __bf16* __restrict__ Wu, int ldwu,
    const float* __restrict__ addu, int asu, const float* __restrict__ mulu, int msu,
    float* __restrict__ outu, int Tu,
    int ztiles, int ntiles)
{
  const int wv = threadIdx.x >> 6, lane = threadIdx.x & 63;
  const int tile = blockIdx.x*4 + wv;
  if (tile >= ntiles) return;
  const __bf16 *A, *W; const float *add, *mul; float* outp;
  int ldw, as, ms, T, lt;
  if (tile < ztiles) { A=Az; W=Wz; ldw=ldwz; add=addz; as=asz; mul=mulz; ms=msz; outp=outz; T=Tz; lt=tile; }
  else               { A=Au; W=Wu; ldw=ldwu; add=addu; as=asu; mul=mulu; ms=msu; outp=outu; T=Tu; lt=tile-ztiles; }
  const int nb = lt & 7;
  const int bn = nb * 64, bm = (lt >> 3) * 64;
  const int col = lane & 15, g = lane >> 4;
  f32x4 acc[4][4] = {};
  for (int k0 = 0; k0 < 512; k0 += 32) {
    const int k = k0 + g*8;
    bf16x8 af[4], bw[4];
#pragma unroll
    for (int i = 0; i < 4; ++i) {
      af[i] = *(const bf16x8*)(A + (size_t)(bm + i*16 + col)*512 + k);
      bw[i] = *(const bf16x8*)(W + (size_t)(bn + i*16 + col)*ldw + k);
    }
#pragma unroll
    for (int i = 0; i < 4; ++i)
#pragma unroll
      for (int j = 0; j < 4; ++j)
        acc[i][j] = __builtin_amdgcn_mfma_f32_16x16x32_bf16(af[i], bw[j], acc[i][j], 0, 0, 0);
  }
#pragma unroll
  for (int mi = 0; mi < 4; ++mi)
#pragma unroll
    for (int r = 0; r < 4; ++r) {
      int m = bm + mi*16 + g*4 + r;
      int b = m & (B_-1), t = m >> 7;
      float p = 0.f;
#pragma unroll
      for (int ni = 0; ni < 4; ++ni) {
        int n = bn + ni*16 + col;
        float v = tanhf(acc[mi][ni][r] + add[(size_t)b*as + n]);
        p += v * mul[(size_t)b*ms + n];
      }
      p += __shfl_xor(p, 1); p += __shfl_xor(p, 2);
      p += __shfl_xor(p, 4); p += __shfl_xor(p, 8);
      if (col == 0) outp[(size_t)nb*(B_*T) + b*T + t] = p;
    }
}

// ---------------------------------------------------------------------------
// Fused per-batch softmax+context for both attentions: blocks 0..127 z, 128..255 u.
// ---------------------------------------------------------------------------
__device__ __forceinline__ void soft_ctx_body(
    const float* __restrict__ partial, const float* __restrict__ enc,
    float* __restrict__ ctx, int T, int b)
{
  const int tid = threadIdx.x;
  __shared__ float sa[256];
  __shared__ float aw[128];
  float s = -INFINITY;
  if (tid < T) {
    s = 0.f;
#pragma unroll
    for (int nb = 0; nb < NB; ++nb) s += partial[(size_t)nb*(B_*T) + b*T + tid];
  }
  sa[tid] = s; __syncthreads();
  for (int o = 128; o > 0; o >>= 1) { if (tid < o) sa[tid] = fmaxf(sa[tid], sa[tid+o]); __syncthreads(); }
  float mx = sa[0]; __syncthreads();
  float e = (tid < T) ? __expf(s - mx) : 0.f;
  sa[tid] = e; __syncthreads();
  for (int o = 128; o > 0; o >>= 1) { if (tid < o) sa[tid] += sa[tid+o]; __syncthreads(); }
  float inv = 1.f / sa[0];
  if (tid < T) aw[tid] = e * inv;
  __syncthreads();
  for (int h = tid; h < H_; h += 256) {
    float acc = 0.f;
    for (int t = 0; t < T; ++t)
      acc += aw[t] * enc[((size_t)t*B_ + b)*H_ + h];
    ctx[(size_t)b*H_ + h] = acc;
  }
}

__global__ __launch_bounds__(256) void attn_soft_ctx2(
    const float* __restrict__ partZ, const float* __restrict__ z_enc, float* __restrict__ zctx,
    const float* __restrict__ partU, const float* __restrict__ u_enc, float* __restrict__ uctx)
{
  if (blockIdx.x < B_) soft_ctx_body(partZ, z_enc, zctx, TZ, blockIdx.x);
  else                 soft_ctx_body(partU, u_enc, uctx, TU, blockIdx.x - B_);
}

// ---------------------------------------------------------------------------
// Build gin (bf16 padded) and cat3b[:, :1024] = [z_ctx, u_ctx] (bf16).
// ---------------------------------------------------------------------------
__global__ __launch_bounds__(256) void concat_kernel(
    const int* __restrict__ m_t, const float* __restrict__ emb,
    const float* __restrict__ uctx, const float* __restrict__ zctx,
    const float* __restrict__ degree,
    __bf16* __restrict__ gin, __bf16* __restrict__ cat3b)
{
  const int b = blockIdx.x, tid = threadIdx.x;
  const float* e = emb + (size_t)m_t[b] * H_;
  for (int i = tid; i < H_; i += 256) {
    float uz = uctx[(size_t)b*H_ + i];
    float zz = zctx[(size_t)b*H_ + i];
    gin[(size_t)b*GINP + i]          = (__bf16)e[i];
    gin[(size_t)b*GINP + H_ + i]     = (__bf16)uz;
    gin[(size_t)b*GINP + 2*H_ + i]   = (__bf16)zz;
    cat3b[(size_t)b*G3 + i]          = (__bf16)zz;
    cat3b[(size_t)b*G3 + H_ + i]     = (__bf16)uz;
  }
  if (tid < 5) gin[(size_t)b*GINP + 3*H_ + tid] = (__bf16)degree[b*5 + tid];
  if (tid >= 5 && tid < 32) gin[(size_t)b*GINP + GIN + (tid-5)] = (__bf16)0.f;
}

// ---------------------------------------------------------------------------
// GRU pointwise; writes hnew (fp32), cat3b[:,1024:1536] (bf16), both outputs.
// ---------------------------------------------------------------------------
__global__ __launch_bounds__(256) void gru_kernel(
    const float* __restrict__ gi, const float* __restrict__ gh,
    const float* __restrict__ hprev,
    float* __restrict__ hnew, __bf16* __restrict__ cat3b,
    float* __restrict__ out1, float* __restrict__ out2)
{
  int idx = blockIdx.x*256 + threadIdx.x;        // B*H
  int b = idx >> 9, h = idx & (H_-1);
  float ir = gi[(size_t)b*G3 + h],        hr = gh[(size_t)b*G3 + h];
  float iz = gi[(size_t)b*G3 + H_ + h],   hz = gh[(size_t)b*G3 + H_ + h];
  float in_= gi[(size_t)b*G3 + 2*H_ + h], hn = gh[(size_t)b*G3 + 2*H_ + h];
  float r = sigmoidf_(ir + hr);
  float z = sigmoidf_(iz + hz);
  float n = tanhf(in_ + r*hn);
  float hv = (1.f - z)*n + z*hprev[idx];
  hnew[idx] = hv;
  cat3b[(size_t)b*G3 + 2*H_ + h] = (__bf16)hv;
  out1[idx] = hv;
  out2[idx] = hv;
}

// ---------------------------------------------------------------------------
// z_score partials -> per-row max + exp
// ---------------------------------------------------------------------------
__global__ __launch_bounds__(64) void zexp_kernel(
    const float* __restrict__ partial, float* __restrict__ e, float* __restrict__ mbuf)
{
  const int b = blockIdx.x, tid = threadIdx.x;   // 64 threads
  __shared__ float sa[64];
  float s = 0.f;
#pragma unroll
  for (int nb = 0; nb < NB; ++nb) s += partial[(size_t)nb*(B_*TZ) + b*TZ + tid];
  sa[tid] = s; __syncthreads();
  for (int o = 32; o > 0; o >>= 1) { if (tid < o) sa[tid] = fmaxf(sa[tid], sa[tid+o]); __syncthreads(); }
  float mx = sa[0];
  e[b*TZ + tid] = __expf(s - mx);
  if (tid == 0) mbuf[b] = mx;
}

// ---------------------------------------------------------------------------
// zbuf[b][v] = log(sum_t e[t] * sr[b,t,v]) + m[b]
// ---------------------------------------------------------------------------
__global__ __launch_bounds__(256) void zcopy_kernel(
    const float* __restrict__ e, const float* __restrict__ mbuf,
    const float* __restrict__ sr, float* __restrict__ zbuf)
{
  const int b = blockIdx.y;
  const int v0 = blockIdx.x*1024 + threadIdx.x*4;
  __shared__ float se[TZ];
  if (threadIdx.x < TZ) se[threadIdx.x] = e[b*TZ + threadIdx.x];
  __syncthreads();
  if (v0 >= VC) return;
  float4 acc = {0.f, 0.f, 0.f, 0.f};
  const float* base = sr + (size_t)b*TZ*VC;
#pragma unroll 4
  for (int t = 0; t < TZ; ++t) {
    float et = se[t];
    float4 x = *(const float4*)(base + (size_t)t*VC + v0);
    acc.x += et*x.x; acc.y += et*x.y; acc.z += et*x.z; acc.w += et*x.w;
  }
  float m = mbuf[b];
  float* out = zbuf + (size_t)b*VC + v0;
  out[0] = __logf(acc.x) + m;
  out[1] = __logf(acc.y) + m;
  out[2] = __logf(acc.z) + m;
  out[3] = __logf(acc.w) + m;
}

// ---------------------------------------------------------------------------
// Final softmax: gen_j = p0+p1+p2+bias (j<V), copy_i = zbuf (i<VC).
// proba = [softmax_gen + softmax_cp[:V], softmax_cp[V:]]
// ---------------------------------------------------------------------------
__global__ __launch_bounds__(256) void final_softmax2(
    const float* __restrict__ p0, const float* __restrict__ p1, const float* __restrict__ p2,
    const float* __restrict__ bias, const float* __restrict__ zbuf, float* __restrict__ out0)
{
  const int b = blockIdx.x, tid = threadIdx.x;
  const float* q0 = p0 + (size_t)b*V_;
  const float* q1 = p1 + (size_t)b*V_;
  const float* q2 = p2 + (size_t)b*V_;
  const float* zr = zbuf + (size_t)b*VC;
  __shared__ float sa[256];
  float mx = -INFINITY;
  for (int i = tid; i < V_; i += 256) mx = fmaxf(mx, q0[i]+q1[i]+q2[i]+bias[i]);
  for (int i = tid; i < VC; i += 256) mx = fmaxf(mx, zr[i]);
  sa[tid] = mx; __syncthreads();
  for (int o = 128; o > 0; o >>= 1) { if (tid < o) sa[tid] = fmaxf(sa[tid], sa[tid+o]); __syncthreads(); }
  mx = sa[0]; __syncthreads();
  float sum = 0.f;
  for (int i = tid; i < V_; i += 256) sum += __expf(q0[i]+q1[i]+q2[i]+bias[i] - mx);
  for (int i = tid; i < VC; i += 256) sum += __expf(zr[i] - mx);
  sa[tid] = sum; __syncthreads();
  for (int o = 128; o > 0; o >>= 1) { if (tid < o) sa[tid] += sa[tid+o]; __syncthreads(); }
  float inv = 1.f / sa[0];
  float* o0 = out0 + (size_t)b*VC;
  for (int j = tid; j < V_; j += 256)
    o0[j] = (__expf(q0[j]+q1[j]+q2[j]+bias[j]-mx) + __expf(zr[j]-mx)) * inv;
  for (int j = tid; j < TZ; j += 256)
    o0[V_ + j] = __expf(zr[V_ + j] - mx) * inv;
}

// ---------------------------------------------------------------------------
extern "C" void kernel_launch(void* const* d_in, const int* in_sizes, int n_in,
                              void* d_out, int out_size, void* d_ws, size_t ws_size,
                              hipStream_t stream)
{
  const float* z_enc   = (const float*)d_in[0];   // (64,128,512)
  const float* u_enc   = (const float*)d_in[1];   // (128,128,512)
  const int*   m_t     = (const int*)  d_in[2];   // (1,128)
  const float* degree  = (const float*)d_in[3];   // (128,5)
  const float* hidden  = (const float*)d_in[4];   // (1,128,512)
  const float* sr      = (const float*)d_in[5];   // (128,64,8064)
  const float* emb     = (const float*)d_in[6];   // (8000,512)
  const float* attn_z_W= (const float*)d_in[7];   // (512,1024)
  const float* attn_z_b= (const float*)d_in[8];
  const float* attn_z_v= (const float*)d_in[9];
  const float* attn_u_W= (const float*)d_in[10];
  const float* attn_u_b= (const float*)d_in[11];
  const float* attn_u_v= (const float*)d_in[12];
  const float* gru_W_ih= (const float*)d_in[13];  // (1536,1541)
  const float* gru_W_hh= (const float*)d_in[14];  // (1536,512)
  const float* gru_b_ih= (const float*)d_in[15];
  const float* gru_b_hh= (const float*)d_in[16];
  const float* proj_W  = (const float*)d_in[17];  // (8000,1536)
  const float* proj_b  = (const float*)d_in[18];
  const float* copy2_W = (const float*)d_in[19];  // (512,512)
  const float* copy2_b = (const float*)d_in[20];

  float* out0 = (float*)d_out;                        // (128, 8064)
  float* out1 = out0 + (size_t)B_*VC;                 // (128, 512)
  float* out2 = out1 + (size_t)B_*H_;                 // (128, 512)

  // Workspace layout — fp32 region
  float* ws    = (float*)d_ws;
  float* hWz   = ws;                      // 65536
  float* hWu   = hWz   + B_*H_;           // 65536
  float* gh    = hWu   + B_*H_;           // 196608
  float* partZ = gh    + B_*G3;           // 8*128*64
  float* partU = partZ + NB*B_*TZ;        // 8*128*128
  float* partC = partU + NB*B_*TU;        // 8*128*64
  float* zctx  = partC + NB*B_*TZ;        // 65536
  float* uctx  = zctx  + B_*H_;           // 65536
  float* gi    = uctx  + B_*H_;           // 196608
  float* hnew  = gi    + B_*G3;           // 65536
  float* ez    = hnew  + B_*H_;           // 8192
  float* mz    = ez    + B_*TZ;           // 128
  float* p0    = mz    + B_;              // 128*8000
  float* p1    = p0    + (size_t)B_*V_;
  float* p2    = p1    + (size_t)B_*V_;
  float* zbuf  = p2    + (size_t)B_*V_;   // 128*8064
  // bf16 region
  __bf16* gin   = (__bf16*)(zbuf + (size_t)B_*VC);   // 128*1568
  __bf16* Wp    = gin   + (size_t)B_*GINP;           // 1536*1568
  __bf16* zb    = Wp    + (size_t)G3*GINP;           // 64*128*512
  __bf16* ub    = zb    + (size_t)TZ*B_*H_;          // 128*128*512
  __bf16* hb    = ub    + (size_t)TU*B_*H_;          // 128*512
  __bf16* zWb   = hb    + (size_t)B_*H_;             // 512*1024
  __bf16* uWb   = zWb   + (size_t)H_*2*H_;           // 512*1024
  __bf16* cWb   = uWb   + (size_t)H_*2*H_;           // 512*512
  __bf16* whhb  = cWb   + (size_t)H_*H_;             // 1536*512
  __bf16* pWb   = whhb  + (size_t)G3*H_;             // 8000*1536
  __bf16* cat3b = pWb   + (size_t)V_*G3;             // 128*1536

  // 1. convert everything to bf16
  cvt_all<<<(CVT_UNITS + 255)/256, 256, 0, stream>>>(
      z_enc, u_enc, hidden, attn_z_W, attn_u_W, copy2_W, gru_W_hh, proj_W,
      zb, ub, hb, zWb, uWb, cWb, whhb, pWb);
  cvt_pad_bf16<<<(int)(((size_t)G3*GINP + 255)/256), 256, 0, stream>>>(gru_W_ih, Wp, G3, GIN, GINP);

  // 2. hidden-side GEMMs (bias folded)
  mfma_gemm_bf16<<<4, 256, 0, stream>>>(hb, H_, zWb, 2*H_, attn_z_b, hWz, H_, H_, 8, 16);
  mfma_gemm_bf16<<<4, 256, 0, stream>>>(hb, H_, uWb, 2*H_, attn_u_b, hWu, H_, H_, 8, 16);
  mfma_gemm_bf16<<<12, 256, 0, stream>>>(hb, H_, whhb, H_, gru_b_hh, gh, G3, H_, 24, 48);

  // 3. fused z+u attention energies (z: 1024 tiles, u: 2048 tiles)
  mfma_energy2<<<768, 256, 0, stream>>>(
      zb, zWb + H_, 2*H_, hWz, H_, attn_z_v, 0, partZ, TZ,
      ub, uWb + H_, 2*H_, hWu, H_, attn_u_v, 0, partU, TU,
      1024, 3072);

  // 4. fused softmax+context
  attn_soft_ctx2<<<2*B_, 256, 0, stream>>>(partZ, z_enc, zctx, partU, u_enc, uctx);

  // 5. GRU
  concat_kernel<<<B_, 256, 0, stream>>>(m_t, emb, uctx, zctx, degree, gin, cat3b);
  mfma_gemm_bf16<<<12, 256, 0, stream>>>(gin, GINP, Wp, GINP, gru_b_ih, gi, G3, GINP, 24, 48);
  gru_kernel<<<(B_*H_)/256, 256, 0, stream>>>(gi, gh, hidden, hnew, cat3b, out1, out2);

  // 6. projection (K-split x3 -> partials)
  mfma_proj<<<188, 256, 0, stream>>>(cat3b, pWb, p0);

  // 7. copy scores (z-path only of the fused energy kernel)
  mfma_energy2<<<256, 256, 0, stream>>>(
      zb, cWb, H_, copy2_b, 0, hnew, H_, partC, TZ,
      zb, cWb, H_, copy2_b, 0, hnew, H_, partC, TZ,
      1024, 1024);
  zexp_kernel<<<B_, 64, 0, stream>>>(partC, ez, mz);
  zcopy_kernel<<<dim3((VC + 1023)/1024, B_), 256, 0, stream>>>(ez, mz, sr, zbuf);

  // 8. final softmax + output assembly
  final_softmax2<<<B_, 256, 0, stream>>>(p0, p1, p2, proj_b, zbuf, out0);
}

// Round 8
// 295.212 us; speedup vs baseline: 3.6704x; 1.2671x over previous
//
#include <hip/hip_runtime.h>
#include <hip/hip_bf16.h>
#include <math.h>

// Problem constants
#define B_   128
#define H_   512
#define TZ   64
#define TU   128
#define V_   8000
#define VC   8064            // V + TZ
#define GIN  1541            // E + 2H + 5
#define GINP 1568            // GIN padded to multiple of 32
#define G3   1536            // 3*H
#define NB   8               // n-blocks per 512-wide energy GEMM

typedef float f32x4 __attribute__((ext_vector_type(4)));
typedef __bf16 bf16x8 __attribute__((ext_vector_type(8)));

__device__ __forceinline__ float sigmoidf_(float x){ return 1.f/(1.f+__expf(-x)); }

__device__ __forceinline__ void cvt8(const float* __restrict__ s, __bf16* __restrict__ d){
  float4 x = *(const float4*)s;
  float4 y = *(const float4*)(s+4);
  bf16x8 r;
  r[0]=(__bf16)x.x; r[1]=(__bf16)x.y; r[2]=(__bf16)x.z; r[3]=(__bf16)x.w;
  r[4]=(__bf16)y.x; r[5]=(__bf16)y.y; r[6]=(__bf16)y.z; r[7]=(__bf16)y.w;
  *(bf16x8*)d = r;
}

// ---------------------------------------------------------------------------
// One-pass fp32->bf16 conversion of all MFMA operands (unit = 8 elems),
// including gru_W_ih with row padding 1541 -> 1568 (scalar, unaligned rows).
// ---------------------------------------------------------------------------
#define U_Z   524288u     // z_enc
#define U_U   1048576u    // u_enc
#define U_H   8192u       // hidden
#define U_ZW  65536u      // attn_z_W
#define U_UW  65536u      // attn_u_W
#define U_CW  32768u      // copy2_W
#define U_WHH 98304u      // gru_W_hh
#define U_PW  1536000u    // proj_W
#define U_WIH 301056u     // gru_W_ih padded: 1536*1568/8
#define CVT_UNITS (U_Z+U_U+U_H+U_ZW+U_UW+U_CW+U_WHH+U_PW+U_WIH)

__global__ __launch_bounds__(256) void cvt_all(
    const float* __restrict__ z, const float* __restrict__ u, const float* __restrict__ hid,
    const float* __restrict__ zW, const float* __restrict__ uW, const float* __restrict__ cW,
    const float* __restrict__ whh, const float* __restrict__ pW, const float* __restrict__ wih,
    __bf16* __restrict__ zb, __bf16* __restrict__ ub, __bf16* __restrict__ hb,
    __bf16* __restrict__ zWb, __bf16* __restrict__ uWb, __bf16* __restrict__ cWb,
    __bf16* __restrict__ whhb, __bf16* __restrict__ pWb, __bf16* __restrict__ Wp)
{
  unsigned t = blockIdx.x*256u + threadIdx.x;
  if (t >= CVT_UNITS) return;
  unsigned o = t;
  if (o >= CVT_UNITS - U_WIH) {           // gru_W_ih pad segment (scalar loads)
    o -= (CVT_UNITS - U_WIH);
    unsigned r = o / (GINP/8), cu = o % (GINP/8);
    int c0 = cu*8;
    const float* src = wih + (size_t)r*GIN;
    bf16x8 v;
#pragma unroll
    for (int e = 0; e < 8; ++e) {
      int c = c0 + e;
      v[e] = (__bf16)((c < GIN) ? src[c] : 0.f);
    }
    *(bf16x8*)(Wp + (size_t)r*GINP + c0) = v;
    return;
  }
  const float* s; __bf16* d;
  if      (o < U_Z)                   { s=z;   d=zb;   }
  else if ((o-=U_Z)   < U_U)          { s=u;   d=ub;   }
  else if ((o-=U_U)   < U_H)          { s=hid; d=hb;   }
  else if ((o-=U_H)   < U_ZW)         { s=zW;  d=zWb;  }
  else if ((o-=U_ZW)  < U_UW)         { s=uW;  d=uWb;  }
  else if ((o-=U_UW)  < U_CW)         { s=cW;  d=cWb;  }
  else if ((o-=U_CW)  < U_WHH)        { s=whh; d=whhb; }
  else     { o-=U_WHH;                  s=pW;  d=pWb;  }
  cvt8(s + (size_t)o*8, d + (size_t)o*8);
}

// ---------------------------------------------------------------------------
// Fused hidden-side GEMMs: hWz (16 tiles), hWu (16), gh (48). 80 tiles total.
// A = hb [128][512], K = 512.
// ---------------------------------------------------------------------------
__global__ __launch_bounds__(256) void hidden3(
    const __bf16* __restrict__ hb,
    const __bf16* __restrict__ zWb, const float* __restrict__ zbias, float* __restrict__ hWz,
    const __bf16* __restrict__ uWb, const float* __restrict__ ubias, float* __restrict__ hWu,
    const __bf16* __restrict__ whhb, const float* __restrict__ hbias, float* __restrict__ gh)
{
  const int wv = threadIdx.x >> 6, lane = threadIdx.x & 63;
  const int tile = blockIdx.x*4 + wv;
  if (tile >= 80) return;
  const __bf16* W; const float* bias; float* C; int ldw, ldc, nbn, lt;
  if (tile < 16)      { W=zWb;  bias=zbias; C=hWz; ldw=2*H_; ldc=H_; nbn=8;  lt=tile; }
  else if (tile < 32) { W=uWb;  bias=ubias; C=hWu; ldw=2*H_; ldc=H_; nbn=8;  lt=tile-16; }
  else                { W=whhb; bias=hbias; C=gh;  ldw=H_;   ldc=G3; nbn=24; lt=tile-32; }
  const int bn = (lt % nbn) * 64, bm = (lt / nbn) * 64;
  const int col = lane & 15, g = lane >> 4;
  f32x4 acc[4][4] = {};
  for (int k0 = 0; k0 < 512; k0 += 32) {
    const int k = k0 + g*8;
    bf16x8 af[4], bw[4];
#pragma unroll
    for (int i = 0; i < 4; ++i) {
      af[i] = *(const bf16x8*)(hb + (size_t)(bm + i*16 + col)*H_ + k);
      bw[i] = *(const bf16x8*)(W  + (size_t)(bn + i*16 + col)*ldw + k);
    }
#pragma unroll
    for (int i = 0; i < 4; ++i)
#pragma unroll
      for (int j = 0; j < 4; ++j)
        acc[i][j] = __builtin_amdgcn_mfma_f32_16x16x32_bf16(af[i], bw[j], acc[i][j], 0, 0, 0);
  }
#pragma unroll
  for (int mi = 0; mi < 4; ++mi)
#pragma unroll
    for (int r = 0; r < 4; ++r) {
      int m = bm + mi*16 + g*4 + r;
#pragma unroll
      for (int ni = 0; ni < 4; ++ni) {
        int n = bn + ni*16 + col;
        C[(size_t)m*ldc + n] = acc[mi][ni][r] + bias[n];
      }
    }
}

// ---------------------------------------------------------------------------
// Fused z+u attention energies (bf16).
//   partial[nb][b*T+t] = sum_{n in nb} tanh(acc + add[b*as+n]) * mul[b*ms+n]
// ---------------------------------------------------------------------------
__global__ __launch_bounds__(256) void mfma_energy2(
    const __bf16* __restrict__ Az, const __bf16* __restrict__ Wz, int ldwz,
    const float* __restrict__ addz, int asz, const float* __restrict__ mulz, int msz,
    float* __restrict__ outz, int Tz,
    const __bf16* __restrict__ Au, const __bf16* __restrict__ Wu, int ldwu,
    const float* __restrict__ addu, int asu, const float* __restrict__ mulu, int msu,
    float* __restrict__ outu, int Tu,
    int ztiles, int ntiles)
{
  const int wv = threadIdx.x >> 6, lane = threadIdx.x & 63;
  const int tile = blockIdx.x*4 + wv;
  if (tile >= ntiles) return;
  const __bf16 *A, *W; const float *add, *mul; float* outp;
  int ldw, as, ms, T, lt;
  if (tile < ztiles) { A=Az; W=Wz; ldw=ldwz; add=addz; as=asz; mul=mulz; ms=msz; outp=outz; T=Tz; lt=tile; }
  else               { A=Au; W=Wu; ldw=ldwu; add=addu; as=asu; mul=mulu; ms=msu; outp=outu; T=Tu; lt=tile-ztiles; }
  const int nb = lt & 7;
  const int bn = nb * 64, bm = (lt >> 3) * 64;
  const int col = lane & 15, g = lane >> 4;
  f32x4 acc[4][4] = {};
  for (int k0 = 0; k0 < 512; k0 += 32) {
    const int k = k0 + g*8;
    bf16x8 af[4], bw[4];
#pragma unroll
    for (int i = 0; i < 4; ++i) {
      af[i] = *(const bf16x8*)(A + (size_t)(bm + i*16 + col)*512 + k);
      bw[i] = *(const bf16x8*)(W + (size_t)(bn + i*16 + col)*ldw + k);
    }
#pragma unroll
    for (int i = 0; i < 4; ++i)
#pragma unroll
      for (int j = 0; j < 4; ++j)
        acc[i][j] = __builtin_amdgcn_mfma_f32_16x16x32_bf16(af[i], bw[j], acc[i][j], 0, 0, 0);
  }
#pragma unroll
  for (int mi = 0; mi < 4; ++mi)
#pragma unroll
    for (int r = 0; r < 4; ++r) {
      int m = bm + mi*16 + g*4 + r;
      int b = m & (B_-1), t = m >> 7;
      float p = 0.f;
#pragma unroll
      for (int ni = 0; ni < 4; ++ni) {
        int n = bn + ni*16 + col;
        float v = tanhf(acc[mi][ni][r] + add[(size_t)b*as + n]);
        p += v * mul[(size_t)b*ms + n];
      }
      p += __shfl_xor(p, 1); p += __shfl_xor(p, 2);
      p += __shfl_xor(p, 4); p += __shfl_xor(p, 8);
      if (col == 0) outp[(size_t)nb*(B_*T) + b*T + t] = p;
    }
}

// ---------------------------------------------------------------------------
// Fused: z+u softmax over partials + both contexts + concat into gin/cat3b.
// One block per batch row.
// ---------------------------------------------------------------------------
__global__ __launch_bounds__(256) void attn_ctx_concat(
    const float* __restrict__ partZ, const float* __restrict__ partU,
    const __bf16* __restrict__ zb, const __bf16* __restrict__ ub,
    const int* __restrict__ m_t, const float* __restrict__ emb,
    const float* __restrict__ degree,
    __bf16* __restrict__ gin, __bf16* __restrict__ cat3b)
{
  const int b = blockIdx.x, tid = threadIdx.x;
  __shared__ float sa[256];
  __shared__ float awz[TZ];
  __shared__ float awu[TU];
  // --- z softmax (T=64) ---
  {
    float s = -INFINITY;
    if (tid < TZ) {
      s = 0.f;
#pragma unroll
      for (int nb = 0; nb < NB; ++nb) s += partZ[(size_t)nb*(B_*TZ) + b*TZ + tid];
    }
    sa[tid] = s; __syncthreads();
    for (int o = 128; o > 0; o >>= 1) { if (tid < o) sa[tid] = fmaxf(sa[tid], sa[tid+o]); __syncthreads(); }
    float mx = sa[0]; __syncthreads();
    float e = (tid < TZ) ? __expf(s - mx) : 0.f;
    sa[tid] = e; __syncthreads();
    for (int o = 128; o > 0; o >>= 1) { if (tid < o) sa[tid] += sa[tid+o]; __syncthreads(); }
    float inv = 1.f / sa[0];
    if (tid < TZ) awz[tid] = e * inv;
    __syncthreads();
  }
  // --- u softmax (T=128) ---
  {
    float s = -INFINITY;
    if (tid < TU) {
      s = 0.f;
#pragma unroll
      for (int nb = 0; nb < NB; ++nb) s += partU[(size_t)nb*(B_*TU) + b*TU + tid];
    }
    sa[tid] = s; __syncthreads();
    for (int o = 128; o > 0; o >>= 1) { if (tid < o) sa[tid] = fmaxf(sa[tid], sa[tid+o]); __syncthreads(); }
    float mx = sa[0]; __syncthreads();
    float e = (tid < TU) ? __expf(s - mx) : 0.f;
    sa[tid] = e; __syncthreads();
    for (int o = 128; o > 0; o >>= 1) { if (tid < o) sa[tid] += sa[tid+o]; __syncthreads(); }
    float inv = 1.f / sa[0];
    if (tid < TU) awu[tid] = e * inv;
    __syncthreads();
  }
  // --- contexts + concat ---
  const float* e = emb + (size_t)m_t[b] * H_;
  for (int h = tid; h < H_; h += 256) {
    float accz = 0.f, accu = 0.f;
    for (int t = 0; t < TZ; ++t) accz += awz[t] * (float)zb[((size_t)t*B_ + b)*H_ + h];
    for (int t = 0; t < TU; ++t) accu += awu[t] * (float)ub[((size_t)t*B_ + b)*H_ + h];
    gin[(size_t)b*GINP + h]          = (__bf16)e[h];
    gin[(size_t)b*GINP + H_ + h]     = (__bf16)accu;
    gin[(size_t)b*GINP + 2*H_ + h]   = (__bf16)accz;
    cat3b[(size_t)b*G3 + h]          = (__bf16)accz;
    cat3b[(size_t)b*G3 + H_ + h]     = (__bf16)accu;
  }
  if (tid < 5) gin[(size_t)b*GINP + 3*H_ + tid] = (__bf16)degree[b*5 + tid];
  if (tid >= 5 && tid < 32) gin[(size_t)b*GINP + GIN + (tid-5)] = (__bf16)0.f;
}

// ---------------------------------------------------------------------------
// GRU input GEMM, K-split x2: tiles 0..47 -> giA (k in [0,800)),
// 48..95 -> giB (k in [800,1568)). No bias (added in gru_kernel).
// ---------------------------------------------------------------------------
__global__ __launch_bounds__(256) void mfma_gru(
    const __bf16* __restrict__ A, const __bf16* __restrict__ W,
    float* __restrict__ giA, float* __restrict__ giB)
{
  const int wv = threadIdx.x >> 6, lane = threadIdx.x & 63;
  const int tile = blockIdx.x*4 + wv;
  if (tile >= 96) return;
  const int half = tile / 48, lt = tile % 48;
  const int bn = (lt % 24) * 64, bm = (lt / 24) * 64;
  const int col = lane & 15, g = lane >> 4;
  const int kbeg = half ? 800 : 0, kend_ = half ? GINP : 800;
  float* C = half ? giB : giA;
  f32x4 acc[4][4] = {};
  for (int k0 = kbeg; k0 < kend_; k0 += 32) {
    const int k = k0 + g*8;
    bf16x8 af[4], bw[4];
#pragma unroll
    for (int i = 0; i < 4; ++i) {
      af[i] = *(const bf16x8*)(A + (size_t)(bm + i*16 + col)*GINP + k);
      bw[i] = *(const bf16x8*)(W + (size_t)(bn + i*16 + col)*GINP + k);
    }
#pragma unroll
    for (int i = 0; i < 4; ++i)
#pragma unroll
      for (int j = 0; j < 4; ++j)
        acc[i][j] = __builtin_amdgcn_mfma_f32_16x16x32_bf16(af[i], bw[j], acc[i][j], 0, 0, 0);
  }
#pragma unroll
  for (int mi = 0; mi < 4; ++mi)
#pragma unroll
    for (int r = 0; r < 4; ++r) {
      int m = bm + mi*16 + g*4 + r;
#pragma unroll
      for (int ni = 0; ni < 4; ++ni)
        C[(size_t)m*G3 + bn + ni*16 + col] = acc[mi][ni][r];
    }
}

// ---------------------------------------------------------------------------
// GRU pointwise: gi = giA+giB+b_ih; writes hnew, cat3b[2H:], both outputs.
// ---------------------------------------------------------------------------
__global__ __launch_bounds__(256) void gru_kernel(
    const float* __restrict__ giA, const float* __restrict__ giB,
    const float* __restrict__ gh, const float* __restrict__ bih,
    const float* __restrict__ hprev,
    float* __restrict__ hnew, __bf16* __restrict__ cat3b,
    float* __restrict__ out1, float* __restrict__ out2)
{
  int idx = blockIdx.x*256 + threadIdx.x;        // B*H
  int b = idx >> 9, h = idx & (H_-1);
  size_t base = (size_t)b*G3;
  float ir = giA[base + h]        + giB[base + h]        + bih[h]        + gh[base + h];
  float iz = giA[base + H_ + h]   + giB[base + H_ + h]   + bih[H_ + h]   + gh[base + H_ + h];
  float in_= giA[base + 2*H_ + h] + giB[base + 2*H_ + h] + bih[2*H_ + h];
  float hn = gh[base + 2*H_ + h];
  float r = sigmoidf_(ir);
  float z = sigmoidf_(iz);
  float n = tanhf(in_ + r*hn);
  float hv = (1.f - z)*n + z*hprev[idx];
  hnew[idx] = hv;
  cat3b[base + 2*H_ + h] = (__bf16)hv;
  out1[idx] = hv;
  out2[idx] = hv;
}

// ---------------------------------------------------------------------------
// Fused projection (K-split x3, 750 tiles) + copy-energy (1024 tiles).
// ---------------------------------------------------------------------------
__global__ __launch_bounds__(256) void proj_copy(
    const __bf16* __restrict__ cat3b, const __bf16* __restrict__ pWb, float* __restrict__ P,
    const __bf16* __restrict__ zb, const __bf16* __restrict__ cWb,
    const float* __restrict__ c2b, const float* __restrict__ hnew,
    float* __restrict__ partC)
{
  const int wv = threadIdx.x >> 6, lane = threadIdx.x & 63;
  const int tile = blockIdx.x*4 + wv;
  const int col = lane & 15, g = lane >> 4;
  if (tile < 750) {
    const int s = tile / 250, t2 = tile % 250;
    const int bn = (t2 % 125) * 64, bm = (t2 / 125) * 64;
    const __bf16* As = cat3b + s*512;
    const __bf16* Ws = pWb + s*512;
    float* C = P + (size_t)s*B_*V_;
    f32x4 acc[4][4] = {};
    for (int k0 = 0; k0 < 512; k0 += 32) {
      const int k = k0 + g*8;
      bf16x8 af[4], bw[4];
#pragma unroll
      for (int i = 0; i < 4; ++i) {
        af[i] = *(const bf16x8*)(As + (size_t)(bm + i*16 + col)*G3 + k);
        bw[i] = *(const bf16x8*)(Ws + (size_t)(bn + i*16 + col)*G3 + k);
      }
#pragma unroll
      for (int i = 0; i < 4; ++i)
#pragma unroll
        for (int j = 0; j < 4; ++j)
          acc[i][j] = __builtin_amdgcn_mfma_f32_16x16x32_bf16(af[i], bw[j], acc[i][j], 0, 0, 0);
    }
#pragma unroll
    for (int mi = 0; mi < 4; ++mi)
#pragma unroll
      for (int r = 0; r < 4; ++r) {
        int m = bm + mi*16 + g*4 + r;
#pragma unroll
        for (int ni = 0; ni < 4; ++ni)
          C[(size_t)m*V_ + bn + ni*16 + col] = acc[mi][ni][r];
      }
  } else if (tile < 750 + 1024) {
    const int lt = tile - 750;
    const int nb = lt & 7;
    const int bn = nb * 64, bm = (lt >> 3) * 64;
    f32x4 acc[4][4] = {};
    for (int k0 = 0; k0 < 512; k0 += 32) {
      const int k = k0 + g*8;
      bf16x8 af[4], bw[4];
#pragma unroll
      for (int i = 0; i < 4; ++i) {
        af[i] = *(const bf16x8*)(zb + (size_t)(bm + i*16 + col)*512 + k);
        bw[i] = *(const bf16x8*)(cWb + (size_t)(bn + i*16 + col)*H_ + k);
      }
#pragma unroll
      for (int i = 0; i < 4; ++i)
#pragma unroll
        for (int j = 0; j < 4; ++j)
          acc[i][j] = __builtin_amdgcn_mfma_f32_16x16x32_bf16(af[i], bw[j], acc[i][j], 0, 0, 0);
    }
#pragma unroll
    for (int mi = 0; mi < 4; ++mi)
#pragma unroll
      for (int r = 0; r < 4; ++r) {
        int m = bm + mi*16 + g*4 + r;
        int b = m & (B_-1), t = m >> 7;
        float p = 0.f;
#pragma unroll
        for (int ni = 0; ni < 4; ++ni) {
          int n = bn + ni*16 + col;
          float v = tanhf(acc[mi][ni][r] + c2b[n]);
          p += v * hnew[(size_t)b*H_ + n];
        }
        p += __shfl_xor(p, 1); p += __shfl_xor(p, 2);
        p += __shfl_xor(p, 4); p += __shfl_xor(p, 8);
        if (col == 0) partC[(size_t)nb*(B_*TZ) + b*TZ + t] = p;
      }
  }
}

// ---------------------------------------------------------------------------
// zcopy with folded zexp: wave 0 computes e[t] = exp(s-max) from partials.
// zbuf[b][v] = log(sum_t e[t]*sr[b,t,v]) + max
// ---------------------------------------------------------------------------
__global__ __launch_bounds__(256) void zcopy_kernel(
    const float* __restrict__ partC, const float* __restrict__ sr,
    float* __restrict__ zbuf)
{
  const int b = blockIdx.y, tid = threadIdx.x;
  __shared__ float se[TZ];
  __shared__ float smx;
  if (tid < TZ) {
    float s = 0.f;
#pragma unroll
    for (int nb = 0; nb < NB; ++nb) s += partC[(size_t)nb*(B_*TZ) + b*TZ + tid];
    float mx = s;
    mx = fmaxf(mx, __shfl_xor(mx, 1));  mx = fmaxf(mx, __shfl_xor(mx, 2));
    mx = fmaxf(mx, __shfl_xor(mx, 4));  mx = fmaxf(mx, __shfl_xor(mx, 8));
    mx = fmaxf(mx, __shfl_xor(mx, 16)); mx = fmaxf(mx, __shfl_xor(mx, 32));
    se[tid] = __expf(s - mx);
    if (tid == 0) smx = mx;
  }
  __syncthreads();
  const int v0 = blockIdx.x*1024 + tid*4;
  if (v0 >= VC) return;
  float4 acc = {0.f, 0.f, 0.f, 0.f};
  const float* base = sr + (size_t)b*TZ*VC;
#pragma unroll 4
  for (int t = 0; t < TZ; ++t) {
    float et = se[t];
    float4 x = *(const float4*)(base + (size_t)t*VC + v0);
    acc.x += et*x.x; acc.y += et*x.y; acc.z += et*x.z; acc.w += et*x.w;
  }
  float m = smx;
  float* out = zbuf + (size_t)b*VC + v0;
  out[0] = __logf(acc.x) + m;
  out[1] = __logf(acc.y) + m;
  out[2] = __logf(acc.z) + m;
  out[3] = __logf(acc.w) + m;
}

// ---------------------------------------------------------------------------
// Final softmax: gen_j = p0+p1+p2+bias (j<V), copy = zbuf.
// proba = [softmax_gen + softmax_cp[:V], softmax_cp[V:]]
// ---------------------------------------------------------------------------
__global__ __launch_bounds__(256) void final_softmax2(
    const float* __restrict__ p0, const float* __restrict__ p1, const float* __restrict__ p2,
    const float* __restrict__ bias, const float* __restrict__ zbuf, float* __restrict__ out0)
{
  const int b = blockIdx.x, tid = threadIdx.x;
  const float* q0 = p0 + (size_t)b*V_;
  const float* q1 = p1 + (size_t)b*V_;
  const float* q2 = p2 + (size_t)b*V_;
  const float* zr = zbuf + (size_t)b*VC;
  __shared__ float sa[256];
  float mx = -INFINITY;
  for (int i = tid; i < V_; i += 256) mx = fmaxf(mx, q0[i]+q1[i]+q2[i]+bias[i]);
  for (int i = tid; i < VC; i += 256) mx = fmaxf(mx, zr[i]);
  sa[tid] = mx; __syncthreads();
  for (int o = 128; o > 0; o >>= 1) { if (tid < o) sa[tid] = fmaxf(sa[tid], sa[tid+o]); __syncthreads(); }
  mx = sa[0]; __syncthreads();
  float sum = 0.f;
  for (int i = tid; i < V_; i += 256) sum += __expf(q0[i]+q1[i]+q2[i]+bias[i] - mx);
  for (int i = tid; i < VC; i += 256) sum += __expf(zr[i] - mx);
  sa[tid] = sum; __syncthreads();
  for (int o = 128; o > 0; o >>= 1) { if (tid < o) sa[tid] += sa[tid+o]; __syncthreads(); }
  float inv = 1.f / sa[0];
  float* o0 = out0 + (size_t)b*VC;
  for (int j = tid; j < V_; j += 256)
    o0[j] = (__expf(q0[j]+q1[j]+q2[j]+bias[j]-mx) + __expf(zr[j]-mx)) * inv;
  for (int j = tid; j < TZ; j += 256)
    o0[V_ + j] = __expf(zr[V_ + j] - mx) * inv;
}

// ---------------------------------------------------------------------------
extern "C" void kernel_launch(void* const* d_in, const int* in_sizes, int n_in,
                              void* d_out, int out_size, void* d_ws, size_t ws_size,
                              hipStream_t stream)
{
  const float* z_enc   = (const float*)d_in[0];
  const float* u_enc   = (const float*)d_in[1];
  const int*   m_t     = (const int*)  d_in[2];
  const float* degree  = (const float*)d_in[3];
  const float* hidden  = (const float*)d_in[4];
  const float* sr      = (const float*)d_in[5];
  const float* emb     = (const float*)d_in[6];
  const float* attn_z_W= (const float*)d_in[7];
  const float* attn_z_b= (const float*)d_in[8];
  const float* attn_z_v= (const float*)d_in[9];
  const float* attn_u_W= (const float*)d_in[10];
  const float* attn_u_b= (const float*)d_in[11];
  const float* attn_u_v= (const float*)d_in[12];
  const float* gru_W_ih= (const float*)d_in[13];
  const float* gru_W_hh= (const float*)d_in[14];
  const float* gru_b_ih= (const float*)d_in[15];
  const float* gru_b_hh= (const float*)d_in[16];
  const float* proj_W  = (const float*)d_in[17];
  const float* proj_b  = (const float*)d_in[18];
  const float* copy2_W = (const float*)d_in[19];
  const float* copy2_b = (const float*)d_in[20];

  float* out0 = (float*)d_out;
  float* out1 = out0 + (size_t)B_*VC;
  float* out2 = out1 + (size_t)B_*H_;

  // Workspace — fp32 region
  float* ws    = (float*)d_ws;
  float* hWz   = ws;                      // 65536
  float* hWu   = hWz   + B_*H_;           // 65536
  float* gh    = hWu   + B_*H_;           // 196608
  float* partZ = gh    + B_*G3;           // 65536
  float* partU = partZ + NB*B_*TZ;        // 131072
  float* partC = partU + NB*B_*TU;        // 65536
  float* giA   = partC + NB*B_*TZ;        // 196608
  float* giB   = giA   + B_*G3;           // 196608
  float* hnew  = giB   + B_*G3;           // 65536
  float* p0    = hnew  + B_*H_;           // 1024000
  float* p1    = p0    + (size_t)B_*V_;
  float* p2    = p1    + (size_t)B_*V_;
  float* zbuf  = p2    + (size_t)B_*V_;   // 1032192
  // bf16 region
  __bf16* gin   = (__bf16*)(zbuf + (size_t)B_*VC);
  __bf16* Wp    = gin   + (size_t)B_*GINP;
  __bf16* zb    = Wp    + (size_t)G3*GINP;
  __bf16* ub    = zb    + (size_t)TZ*B_*H_;
  __bf16* hb    = ub    + (size_t)TU*B_*H_;
  __bf16* zWb   = hb    + (size_t)B_*H_;
  __bf16* uWb   = zWb   + (size_t)H_*2*H_;
  __bf16* cWb   = uWb   + (size_t)H_*2*H_;
  __bf16* whhb  = cWb   + (size_t)H_*H_;
  __bf16* pWb   = whhb  + (size_t)G3*H_;
  __bf16* cat3b = pWb   + (size_t)V_*G3;

  // 1. convert everything to bf16 (incl. padded gru_W_ih)
  cvt_all<<<(CVT_UNITS + 255)/256, 256, 0, stream>>>(
      z_enc, u_enc, hidden, attn_z_W, attn_u_W, copy2_W, gru_W_hh, proj_W, gru_W_ih,
      zb, ub, hb, zWb, uWb, cWb, whhb, pWb, Wp);

  // 2. fused hidden-side GEMMs
  hidden3<<<20, 256, 0, stream>>>(hb, zWb, attn_z_b, hWz, uWb, attn_u_b, hWu, whhb, gru_b_hh, gh);

  // 3. fused z+u attention energies
  mfma_energy2<<<768, 256, 0, stream>>>(
      zb, zWb + H_, 2*H_, hWz, H_, attn_z_v, 0, partZ, TZ,
      ub, uWb + H_, 2*H_, hWu, H_, attn_u_v, 0, partU, TU,
      1024, 3072);

  // 4. fused softmax + context + concat
  attn_ctx_concat<<<B_, 256, 0, stream>>>(partZ, partU, zb, ub, m_t, emb, degree, gin, cat3b);

  // 5. GRU input GEMM (K-split x2) + pointwise
  mfma_gru<<<24, 256, 0, stream>>>(gin, Wp, giA, giB);
  gru_kernel<<<(B_*H_)/256, 256, 0, stream>>>(giA, giB, gh, gru_b_ih, hidden, hnew, cat3b, out1, out2);

  // 6. fused projection + copy-energy (1774 tiles)
  proj_copy<<<444, 256, 0, stream>>>(cat3b, pWb, p0, zb, cWb, copy2_b, hnew, partC);

  // 7. zcopy (zexp folded in)
  zcopy_kernel<<<dim3((VC + 1023)/1024, B_), 256, 0, stream>>>(partC, sr, zbuf);

  // 8. final softmax + output assembly
  final_softmax2<<<B_, 256, 0, stream>>>(p0, p1, p2, proj_b, zbuf, out0);
}